// Round 8
// baseline (223.686 us; speedup 1.0000x reference)
//
#include <hip/hip_runtime.h>
#include <math.h>

#define B_   4096
#define S_   64
#define H_   128
#define N_   (B_*S_)

// ---- workspace float offsets ----
#define WS_WC    0        // [384][16]  combined obs->gi weights (padded f=16)
#define WS_BC    6144     // [384]      combined gi bias
#define WS_WAP   6528     // [128][16]  padded enc_air_w
#define WS_WQP   8576     // [128][128] wq * qln_w (fp32 copy)
#define WS_SQ    24960    // [128] row sums of wqp
#define WS_EQ    25088    // [128] wq@qln_b + bq
#define WS_KC    25216    // [128][4]  (wk*klnw)@enc_m_w
#define WS_EK1   25728    // [128] (wk*klnw)@enc_m_b
#define WS_SK    25856    // [128] rowsum(wk*klnw)
#define WS_EK2   25984    // [128] wk@kln_b + bk
#define WS_VC    26112    // [128][4]  wv@enc_m_w
#define WS_VB    26624    // [128] wv@enc_m_b + bv
#define WS_MV    26752    // [4] mean weights for keys_raw mean
#define WS_QQ    26756    // [16] 4x4 quadratic form for E[y^2]
#define WS_QLIN  26772    // [4]
#define WS_MBC   26776
#define WS_C0    26777
// packed bf16 region (shorts): GA[0..4095] (rows 0..27 + ones row 31), GC5[4096..8191],
// fcw-frag[8192..10239], mm=2 mlp0 @32768, mm=3 mlp1 @49152
#define WS_PB    27392
#define WS_WO2T  (WS_PB + 5120)   // fp32 [21][128] Wo2 transposed (shifted past fcw frag)
#define WS_SROW  (WS_PB + 7808)   // fp32 [28]
#define WS_EROW  (WS_PB + 7836)   // fp32 [28]  (contiguous after SROW)
#define WS_GB    60160    // gru packed bf16 B-frags: 65536 ushort (32768 floats)
#define WS_AIR   92928    // air_feat buffer: bf16 [N_][128] ushort
#define TOKS     64       // attnmlp tokens per block

typedef __attribute__((ext_vector_type(8))) short bf16x8;
typedef __attribute__((ext_vector_type(4))) float f32x4;

extern "C" __device__ float __ocml_native_exp2_f32(float);   // single v_exp_f32

__device__ __forceinline__ unsigned short f2bf(float f){   // RNE fp32->bf16
    union { float f; unsigned u; } v; v.f = f;
    unsigned r = v.u + 0x7FFF + ((v.u >> 16) & 1);
    return (unsigned short)(r >> 16);
}
__device__ __forceinline__ float bf2f(unsigned short u){
    union { unsigned u; float f; } v; v.u = ((unsigned)u) << 16;
    return v.f;
}
// RNE pack of 2 f32 -> 1 u32 of 2 bf16 (low = a, high = b); single VALU instr
__device__ __forceinline__ unsigned cvtpk_bf16(float a, float b){
    unsigned r;
    asm("v_cvt_pk_bf16_f32 %0, %1, %2" : "=v"(r) : "v"(a), "v"(b));
    return r;
}

#define KL_SCALE (-1.4426950408889634f)   // -log2(e): R/Z gates
#define KN_SCALE ( 2.8853900817779268f)   // 2*log2(e): N/G gates

// ---------------- precompute folded weights + mlp bf16 B-frags ----------------
__global__ void precompute_kernel(
    const float* __restrict__ enc_air_w, const float* __restrict__ enc_air_b,
    const float* __restrict__ enc_m_w,  const float* __restrict__ enc_m_b,
    const float* __restrict__ gru_wih,  const float* __restrict__ gru_bih,
    const float* __restrict__ qln_w, const float* __restrict__ qln_b,
    const float* __restrict__ kln_w, const float* __restrict__ kln_b,
    const float* __restrict__ attn_in_w, const float* __restrict__ attn_in_b,
    const float* __restrict__ attn_out_w,
    const float* __restrict__ mlp0_w, const float* __restrict__ mlp1_w,
    float* __restrict__ ws)
{
    int i = blockIdx.x*blockDim.x + threadIdx.x;
    if (i < 6144) {                       // Wc[o][f] = sum_k wih[o][k]*Wa[k][f]
        int o = i>>4, f = i&15; float a = 0.f;
        if (f < 15) for (int k=0;k<128;k++) a = fmaf(gru_wih[o*128+k], enc_air_w[k*15+f], a);
        ws[WS_WC+i] = a;
    } else if (i < 6528) {                // bc
        int o = i-6144; float a = gru_bih[o];
        for (int k=0;k<128;k++) a = fmaf(gru_wih[o*128+k], enc_air_b[k], a);
        ws[WS_BC+o] = a;
    } else if (i < 8576) {                // Wap padded
        int idx = i-6528; int j = idx>>4, f = idx&15;
        ws[WS_WAP+idx] = (f<15) ? enc_air_w[j*15+f] : 0.f;
    } else if (i < 24960) {               // wqp (fp32 copy)
        int idx = i-8576; int o = idx>>7, j = idx&127;
        ws[WS_WQP+idx] = attn_in_w[o*128+j]*qln_w[j];
    } else if (i < 25088) {               // sq
        int o = i-24960; float a=0.f;
        for (int j=0;j<128;j++) a = fmaf(attn_in_w[o*128+j], qln_w[j], a);
        ws[WS_SQ+o]=a;
    } else if (i < 25216) {               // eq
        int o = i-25088; float a = attn_in_b[o];
        for (int j=0;j<128;j++) a = fmaf(attn_in_w[o*128+j], qln_b[j], a);
        ws[WS_EQ+o]=a;
    } else if (i < 25728) {               // Kc
        int idx = i-25216; int o = idx>>2, f = idx&3; float a=0.f;
        for (int j=0;j<128;j++) a = fmaf(attn_in_w[(128+o)*128+j]*kln_w[j], enc_m_w[j*4+f], a);
        ws[WS_KC+idx]=a;
    } else if (i < 25856) {               // ek1
        int o = i-25728; float a=0.f;
        for (int j=0;j<128;j++) a = fmaf(attn_in_w[(128+o)*128+j]*kln_w[j], enc_m_b[j], a);
        ws[WS_EK1+o]=a;
    } else if (i < 25984) {               // sk
        int o = i-25856; float a=0.f;
        for (int j=0;j<128;j++) a = fmaf(attn_in_w[(128+o)*128+j], kln_w[j], a);
        ws[WS_SK+o]=a;
    } else if (i < 26112) {               // ek2
        int o = i-25984; float a = attn_in_b[128+o];
        for (int j=0;j<128;j++) a = fmaf(attn_in_w[(128+o)*128+j], kln_b[j], a);
        ws[WS_EK2+o]=a;
    } else if (i < 26624) {               // Vc
        int idx = i-26112; int o = idx>>2, f = idx&3; float a=0.f;
        for (int j=0;j<128;j++) a = fmaf(attn_in_w[(256+o)*128+j], enc_m_w[j*4+f], a);
        ws[WS_VC+idx]=a;
    } else if (i < 26752) {               // vb
        int o = i-26624; float a = attn_in_b[256+o];
        for (int j=0;j<128;j++) a = fmaf(attn_in_w[(256+o)*128+j], enc_m_b[j], a);
        ws[WS_VB+o]=a;
    } else if (i < 26756) {               // Mv
        int f = i-26752; float a=0.f;
        for (int j=0;j<128;j++) a += enc_m_w[j*4+f];
        ws[WS_MV+f]=a*(1.f/128.f);
    } else if (i < 26772) {               // QQ
        int idx = i-26756; int a4 = idx>>2, b4 = idx&3; float a=0.f;
        for (int j=0;j<128;j++) a = fmaf(enc_m_w[j*4+a4], enc_m_w[j*4+b4], a);
        ws[WS_QQ+idx]=a*(1.f/128.f);
    } else if (i < 26776) {               // qlin
        int f = i-26772; float a=0.f;
        for (int j=0;j<128;j++) a = fmaf(enc_m_b[j], enc_m_w[j*4+f], a);
        ws[WS_QLIN+f]=a*(2.f/128.f);
    } else if (i == 26776) {
        float a=0.f; for (int j=0;j<128;j++) a += enc_m_b[j];
        ws[WS_MBC]=a*(1.f/128.f);
    } else if (i == 26777) {
        float a=0.f; for (int j=0;j<128;j++) a = fmaf(enc_m_b[j], enc_m_b[j], a);
        ws[WS_C0]=a*(1.f/128.f);
    } else if (i >= 32768 && i < 98304) {
        // mlp bf16 B-frags (mm=2: mlp0, mm=3: mlp1)
        int idx = i - 32768;              // 0..65535
        int mm = idx>>14;
        if (mm >= 2) {
            int i8 = idx & 7, l = (idx>>3)&63, p = (idx>>9)&3, wv = (idx>>11)&7;
            int n = 16*wv + (l&15);
            int k = 32*p + ((l>>4)<<3) + i8;
            float v = (mm==2) ? mlp0_w[n*128+k] : mlp1_w[n*128+k];
            ((unsigned short*)(ws+WS_PB))[idx] = f2bf(v);
        }
    }
}

// ---------------- pack GRU bf16 B-frags (gate-scaled for exp2 finalize) ----------
__global__ void pack_gru_kernel(const float* __restrict__ whh, float* __restrict__ ws)
{
    int idx = blockIdx.x*blockDim.x + threadIdx.x;   // [0, 65536)
    int i8 = idx&7, l=(idx>>3)&63, w=(idx>>9)&7, f=idx>>12;
    int n = 16*w + (l&15);
    int k = ((l>>4)<<3) + i8;       // 0..31 within chunk
    float v = 0.f;
    if (f < 5) {
        int kk = f*32 + k;
        if (kk < 128) v = whh[n*128 + kk];
        else { int kl = kk-128; if (kl<16) v = ws[WS_WC + n*16 + kl]; }
        v *= KL_SCALE;
    } else if (f < 10) {
        int kk = (f-5)*32 + k;
        if (kk < 128) v = whh[(128+n)*128 + kk];
        else { int kl = kk-128; if (kl<16) v = ws[WS_WC + (128+n)*16 + kl]; }
        v *= KL_SCALE;
    } else if (f < 14) {
        int kk = (f-10)*32 + k;
        v = whh[(256+n)*128 + kk] * KN_SCALE;
    } else if (f == 14) {
        if (k < 16) v = ws[WS_WC + (256+n)*16 + k] * KN_SCALE;
    } else {
        if (k < 16) v = ws[WS_WAP + n*16 + k];
    }
    ((unsigned short*)(ws+WS_GB))[idx] = f2bf(v);
}

// ---------------- pack2: GA (score projections + ones-row), Srow/Erow, Wo2T ------
__global__ void pack2_kernel(const float* __restrict__ wo, const float* __restrict__ bo,
                             float* __restrict__ ws)
{
    int i = blockIdx.x*blockDim.x + threadIdx.x;   // 27*256 = 6912
    if (i < 4096) {                                // GA packed bf16 (2 col-tiles x 4 ksteps)
        int i8=i&7, l=(i>>3)&63, p=(i>>9)&3, ct=(i>>11)&1;
        int r = 16*ct + (l&15);
        int k = 32*p + ((l>>4)<<3) + i8;
        float v = 0.f;
        if (r < 28){
            int h = r/7, u = r - h*7;
            float a = 0.f;
            for (int d5=0; d5<32; d5++){
                int d = h*32 + d5;
                float c = (u<4) ? ws[WS_KC + d*4 + u]
                        : (u==4) ? ws[WS_EK1 + d]
                        : (u==5) ? ws[WS_SK + d]
                        :          ws[WS_EK2 + d];
                a = fmaf(c, ws[WS_WQP + d*128 + k], a);
            }
            v = a;
        } else if (r == 31) {
            v = 1.f;                               // ones-row: GEMM A col 31 = sum(X)
        }
        ((unsigned short*)(ws+WS_PB))[i] = f2bf(v);
    } else if (i < 4152) {                         // Srow / Erow
        int j = i - 4096; int r = j % 28; int era = j / 28;
        int h = r/7, u = r - h*7;
        float a = 0.f;
        for (int d5=0; d5<32; d5++){
            int d = h*32 + d5;
            float c = (u<4) ? ws[WS_KC + d*4 + u]
                    : (u==4) ? ws[WS_EK1 + d]
                    : (u==5) ? ws[WS_SK + d]
                    :          ws[WS_EK2 + d];
            a = fmaf(c, ws[(era ? WS_EQ : WS_SQ) + d], a);
        }
        ws[(era ? WS_EROW : WS_SROW) + r] = a;
    } else if (i >= 4224 && i < 6912) {            // Wo2T[c][o]; c=20 -> bo
        int j = i - 4224; int c = j>>7, o = j&127;
        float a;
        if (c == 20) a = bo[o];
        else {
            int h = c/5, u = c - h*5;
            a = 0.f;
            for (int d5=0; d5<32; d5++){
                int d = h*32 + d5;
                float cv = (u<4) ? ws[WS_VC + d*4 + u] : ws[WS_VB + d];
                a = fmaf(wo[o*128 + d], cv, a);
            }
        }
        ws[WS_WO2T + c*128 + o] = a;
    }
}

// ---------------- pack3: GC5 = mlp0_w @ Wo2 + fcw B-frag ----------------
__global__ void pack3_kernel(const float* __restrict__ mlp0_w,
                             const float* __restrict__ fcw,
                             float* __restrict__ ws)
{
    int i = blockIdx.x*blockDim.x + threadIdx.x;   // 24 blocks x 256 = 6144
    if (i < 4096){
        int i8=i&7, l=(i>>3)&63, w=(i>>9)&7;
        int n = 16*w + (l&15);
        int c = ((l>>4)<<3) + i8;                  // 0..31 (cols 128..159 of Wc)
        float v = 0.f;
        if (c < 21){
            float a = 0.f;
            const float* wo2 = ws + WS_WO2T + c*128;
            for (int o=0;o<128;o++) a = fmaf(mlp0_w[n*128+o], wo2[o], a);
            v = a;
        }
        ((unsigned short*)(ws+WS_PB))[4096 + i] = f2bf(v);
    } else {
        // fcw B-frag: col 0 = fcw[k], other cols 0.  2048 shorts at pb[8192..]
        int j = i - 4096;                          // 0..2047
        int i8=j&7, l=(j>>3)&63, p=(j>>9)&3;
        int k = 32*p + ((l>>4)<<3) + i8;
        float v = ((l&15)==0) ? fcw[k] : 0.f;
        ((unsigned short*)(ws+WS_PB))[8192 + j] = f2bf(v);
    }
}

// ---------------- Kernel A v8: GRU — split MFMA chains, cvt_pk everywhere ---------
__global__ __launch_bounds__(512) void gru_kernel(
    const float* __restrict__ obs, const float* __restrict__ h0,
    const float* __restrict__ bhh, const float* __restrict__ ba,
    const float* __restrict__ ws,
    unsigned short* __restrict__ air, float* __restrict__ out)
{
    __shared__ __align__(16) unsigned short Abf[2][16*136];      // h bf16, pitch 136
    __shared__ __align__(16) unsigned short obs_lds[64*16*24];   // [s][tok][24] bf16
    __shared__ __align__(16) unsigned short zero16[8];

    const int t = threadIdx.x;
    const int w = t>>6;          // wave 0..7
    const int l = t&63;
    const int quad = l>>4;
    const int col  = l&15;
    const int jj   = 16*w + col; // output column j
    const int row0 = blockIdx.x*16;

    const unsigned short* gb = (const unsigned short*)(ws + WS_GB);
    bf16x8 bf[16];
    #pragma unroll
    for (int f=0; f<16; f++) bf[f] = *(const bf16x8*)&gb[(f*8 + w)*512 + l*8];

    // scaled biases -> loop-invariant MFMA C-operand splats
    const float bcrt = KL_SCALE*(ws[WS_BC+jj]     + bhh[jj]);
    const float bczt = KL_SCALE*(ws[WS_BC+128+jj] + bhh[128+jj]);
    const float bcn  = KN_SCALE*ws[WS_BC+256+jj];
    const float bhn  = KN_SCALE*bhh[256+jj];
    const float baj  = ba[jj];
    const f32x4 cR = {bcrt,bcrt,bcrt,bcrt};
    const f32x4 cZ = {bczt,bczt,bczt,bczt};
    const f32x4 cG = {bcn,bcn,bcn,bcn};
    const f32x4 cE = {baj,baj,baj,baj};
    const f32x4 cN = {bhn,bhn,bhn,bhn};
    const f32x4 c0 = {0.f,0.f,0.f,0.f};

    float hreg[4];
    #pragma unroll
    for (int reg=0; reg<4; reg++)
        hreg[reg] = h0[(size_t)(row0+quad*4+reg)*128 + jj];

    if (t < 8) zero16[t] = 0;

    {
        int rr = t>>5, c0i = (t&31)*4;
        float4 hv = *(const float4*)&h0[(size_t)(row0+rr)*128 + c0i];
        unsigned lo = cvtpk_bf16(hv.x, hv.y);
        unsigned hi = cvtpk_bf16(hv.z, hv.w);
        unsigned long long pk = (unsigned long long)lo | ((unsigned long long)hi << 32);
        *(unsigned long long*)&Abf[0][rr*136 + c0i] = pk;
    }

    #pragma unroll
    for (int it=0; it<8; it++){
        int pair = it*128 + (t>>2);      // (tok,s) pair, 4 lanes each
        int sub  = t&3;
        int tok = pair>>6, s = pair&63;
        const float* op = &obs[((size_t)(row0+tok)*64 + s)*15 + sub*4];
        float o0 = op[0];
        float o1 = (sub*4+1<15) ? op[1] : 0.f;
        float o2 = (sub*4+2<15) ? op[2] : 0.f;
        float o3 = (sub*4+3<15) ? op[3] : 0.f;
        if (sub==3){ o3 = 0.f; }
        unsigned lo = cvtpk_bf16(o0, o1);
        unsigned hi = cvtpk_bf16(o2, o3);
        unsigned long long pk = (unsigned long long)lo | ((unsigned long long)hi << 32);
        *(unsigned long long*)&obs_lds[(s*16+tok)*24 + sub*4] = pk;
    }
    __syncthreads();

    // per-reg air pointers (reg offsets exceed the 13-bit store immediate)
    unsigned short* ap0 = air + (size_t)(row0 + quad*4 + 0)*8192 + jj;
    unsigned short* ap1 = air + (size_t)(row0 + quad*4 + 1)*8192 + jj;
    unsigned short* ap2 = air + (size_t)(row0 + quad*4 + 2)*8192 + jj;
    unsigned short* ap3 = air + (size_t)(row0 + quad*4 + 3)*8192 + jj;
    const int anb = (quad*4)*136 + jj;   // An short-index base (rows +136)

    // prologue: obs-only MFMA accs for step 0 (biases ride in C)
    f32x4 oR, oZ, oG, oE;
    {
        const unsigned short* osrc = (quad<2)
            ? &obs_lds[(0*16+col)*24 + quad*8] : &zero16[0];
        bf16x8 a4 = *(const bf16x8*)osrc;
        oR = __builtin_amdgcn_mfma_f32_16x16x32_bf16(a4, bf[4],  cR, 0,0,0);
        oZ = __builtin_amdgcn_mfma_f32_16x16x32_bf16(a4, bf[9],  cZ, 0,0,0);
        oG = __builtin_amdgcn_mfma_f32_16x16x32_bf16(a4, bf[14], cG, 0,0,0);
        oE = __builtin_amdgcn_mfma_f32_16x16x32_bf16(a4, bf[15], cE, 0,0,0);
    }

    unsigned short* const A0 = &Abf[0][0];
    unsigned short* const A1 = &Abf[1][0];

// OFF: air store offset (0 or 128); chains split 2+2 for latency
#define GRU_STEP(S, AC, AN, OFF)                                                   \
    {                                                                              \
        bf16x8 a0 = *(const bf16x8*)&(AC)[col*136 +  0 + quad*8];                  \
        bf16x8 a1 = *(const bf16x8*)&(AC)[col*136 + 32 + quad*8];                  \
        bf16x8 a2 = *(const bf16x8*)&(AC)[col*136 + 64 + quad*8];                  \
        bf16x8 a3 = *(const bf16x8*)&(AC)[col*136 + 96 + quad*8];                  \
        f32x4 aR = oR, aZ = oZ, aN = cN;                                           \
        f32x4 aR2 = c0, aZ2 = c0, aN2 = c0;                                        \
        aR  = __builtin_amdgcn_mfma_f32_16x16x32_bf16(a0, bf[0],  aR,  0,0,0);     \
        aR2 = __builtin_amdgcn_mfma_f32_16x16x32_bf16(a1, bf[1],  aR2, 0,0,0);     \
        aN  = __builtin_amdgcn_mfma_f32_16x16x32_bf16(a0, bf[10], aN,  0,0,0);     \
        aN2 = __builtin_amdgcn_mfma_f32_16x16x32_bf16(a1, bf[11], aN2, 0,0,0);     \
        aR  = __builtin_amdgcn_mfma_f32_16x16x32_bf16(a2, bf[2],  aR,  0,0,0);     \
        aR2 = __builtin_amdgcn_mfma_f32_16x16x32_bf16(a3, bf[3],  aR2, 0,0,0);     \
        aN  = __builtin_amdgcn_mfma_f32_16x16x32_bf16(a2, bf[12], aN,  0,0,0);     \
        aN2 = __builtin_amdgcn_mfma_f32_16x16x32_bf16(a3, bf[13], aN2, 0,0,0);     \
        aZ  = __builtin_amdgcn_mfma_f32_16x16x32_bf16(a0, bf[5],  aZ,  0,0,0);     \
        aZ2 = __builtin_amdgcn_mfma_f32_16x16x32_bf16(a1, bf[6],  aZ2, 0,0,0);     \
        aZ  = __builtin_amdgcn_mfma_f32_16x16x32_bf16(a2, bf[7],  aZ,  0,0,0);     \
        aZ2 = __builtin_amdgcn_mfma_f32_16x16x32_bf16(a3, bf[8],  aZ2, 0,0,0);     \
        f32x4 nR, nZ, nG, nE;                                                      \
        if ((S) < 63){                                                             \
            const unsigned short* osrc = (quad<2)                                  \
                ? &obs_lds[(((S)+1)*16+col)*24 + quad*8] : &zero16[0];             \
            bf16x8 a4 = *(const bf16x8*)osrc;                                      \
            nR = __builtin_amdgcn_mfma_f32_16x16x32_bf16(a4, bf[4],  cR, 0,0,0);   \
            nZ = __builtin_amdgcn_mfma_f32_16x16x32_bf16(a4, bf[9],  cZ, 0,0,0);   \
            nG = __builtin_amdgcn_mfma_f32_16x16x32_bf16(a4, bf[14], cG, 0,0,0);   \
            nE = __builtin_amdgcn_mfma_f32_16x16x32_bf16(a4, bf[15], cE, 0,0,0);   \
        }                                                                          \
        float hnv[4], avv[4];                                                      \
        _Pragma("unroll")                                                          \
        for (int reg=0; reg<4; reg++){                                             \
            float rg = __builtin_amdgcn_rcpf(1.f + __ocml_native_exp2_f32(aR[reg]+aR2[reg]));\
            float zg = __builtin_amdgcn_rcpf(1.f + __ocml_native_exp2_f32(aZ[reg]+aZ2[reg]));\
            float nx = fmaf(rg, aN[reg]+aN2[reg], oG[reg]);                        \
            float e2 = __ocml_native_exp2_f32(nx);                                 \
            float ng = 1.f - 2.f*__builtin_amdgcn_rcpf(e2 + 1.f);                  \
            float hn = fmaf(zg, hreg[reg]-ng, ng);                                 \
            hreg[reg] = hn;                                                        \
            hnv[reg] = hn;                                                         \
            avv[reg] = hn + oE[reg];                                               \
        }                                                                          \
        unsigned ph01 = cvtpk_bf16(hnv[0], hnv[1]);                                \
        unsigned ph23 = cvtpk_bf16(hnv[2], hnv[3]);                                \
        unsigned pa01 = cvtpk_bf16(avv[0], avv[1]);                                \
        unsigned pa23 = cvtpk_bf16(avv[2], avv[3]);                                \
        (AN)[anb        ] = (unsigned short)ph01;                                  \
        (AN)[anb + 136  ] = (unsigned short)(ph01 >> 16);                          \
        (AN)[anb + 272  ] = (unsigned short)ph23;                                  \
        (AN)[anb + 408  ] = (unsigned short)(ph23 >> 16);                          \
        ap0[OFF] = (unsigned short)pa01;  ap1[OFF] = (unsigned short)(pa01 >> 16); \
        ap2[OFF] = (unsigned short)pa23;  ap3[OFF] = (unsigned short)(pa23 >> 16); \
        if ((S) < 63){ oR = nR; oZ = nZ; oG = nG; oE = nE; }                       \
        asm volatile("s_waitcnt lgkmcnt(0)" ::: "memory");                         \
        __builtin_amdgcn_s_barrier();                                              \
        __builtin_amdgcn_sched_barrier(0);                                         \
    }

    for (int s = 0; s < 64; s += 2){
        GRU_STEP(s,   A0, A1, 0)
        GRU_STEP(s+1, A1, A0, 128)
        ap0 += 256; ap1 += 256; ap2 += 256; ap3 += 256;
    }
#undef GRU_STEP

    #pragma unroll
    for (int reg=0; reg<4; reg++)
        out[(size_t)N_ + (size_t)(row0+quad*4+reg)*128 + jj] = hreg[reg];
}

// ---------------- Kernel B v6: attn+MLP (exp2 softmax, cvt_pk epilogues) ----------
__global__ __launch_bounds__(512) void attnmlp_kernel(
    const float* __restrict__ obs,
    const float* __restrict__ ws,
    const float* __restrict__ b0, const float* __restrict__ b1,
    const float* __restrict__ fcb,
    const unsigned short* __restrict__ air, float* __restrict__ out)
{
    __shared__ __align__(16) unsigned short U_bf[TOKS*168];
    __shared__ __align__(16) unsigned short H1_bf[TOKS*136];
    __shared__ float praw[TOKS*28];
    __shared__ float obs_m[TOKS][8];
    __shared__ float sm_s[TOKS], s2_s[TOKS];
    __shared__ float kmu_s[TOKS][2], krs_s[TOKS][2];
    __shared__ int   kmask_s[TOKS][2];
    __shared__ float sero[56];

    const int t = threadIdx.x;
    const int w = t>>6;
    const int l = t&63;
    const int quad = l>>4;
    const int col  = l&15;
    const int jj   = 16*w + col;
    const int n0 = blockIdx.x*TOKS;

    const unsigned short* pb = (const unsigned short*)(ws + WS_PB);

    {
        const int tok0 = t>>3, sub = t&7;
        const unsigned short* apx = &air[(size_t)(n0+tok0)*128 + sub*16];
        uint4 x0 = *(const uint4*)apx;
        uint4 x1 = *(const uint4*)(apx+8);
        *(uint4*)&U_bf[tok0*168 + sub*16]     = x0;
        *(uint4*)&U_bf[tok0*168 + sub*16 + 8] = x1;
        if (sub < 5){
            #pragma unroll
            for (int c=0;c<4;c++) U_bf[tok0*168 + 148 + sub*4 + c] = 0;
        }
        obs_m[tok0][sub] = obs[(size_t)(n0+tok0)*15 + sub];
    }
    if (t < 128){
        int rr = t>>1, mi = t&1;
        const float* mp = &obs[(size_t)(n0+rr)*15 + mi*4];
        float m0=mp[0], m1=mp[1], m2=mp[2], m3=mp[3];
        const float tol1 = 1e-8f + 1e-5f, tol0 = 1e-8f;
        kmask_s[rr][mi] = (fabsf(m0-1.f)<=tol1)&&(fabsf(m1)<=tol0)&&
                          (fabsf(m2-1.f)<=tol1)&&(fabsf(m3)<=tol0);
        float mv[4]={m0,m1,m2,m3};
        float mu = ws[WS_MBC];
        #pragma unroll
        for (int f=0;f<4;f++) mu = fmaf(ws[WS_MV+f], mv[f], mu);
        float e2 = ws[WS_C0];
        #pragma unroll
        for (int a4=0;a4<4;a4++){
            e2 = fmaf(ws[WS_QLIN+a4], mv[a4], e2);
            #pragma unroll
            for (int b4=0;b4<4;b4++) e2 = fmaf(ws[WS_QQ+a4*4+b4]*mv[a4], mv[b4], e2);
        }
        float var = e2 - mu*mu;
        kmu_s[rr][mi]=mu; krs_s[rr][mi]=rsqrtf(var+1e-5f);
    }
    if (t < 56) sero[t] = ws[WS_SROW + t];
    __syncthreads();

    {
        const int tt = w>>1, ct = w&1;
        const int jA = ct*16 + col;
        bf16x8 afr[4];
        #pragma unroll
        for (int p=0;p<4;p++)
            afr[p] = *(const bf16x8*)&U_bf[(tt*16+col)*168 + p*32 + quad*8];
        f32x4 acc = {0.f,0.f,0.f,0.f};
        #pragma unroll
        for (int p=0;p<4;p++)
            acc = __builtin_amdgcn_mfma_f32_16x16x32_bf16(afr[p], *(const bf16x8*)&pb[((ct*4+p)*64 + l)*8], acc, 0,0,0);
        if (ct == 1){
            f32x4 accX = {0.f,0.f,0.f,0.f};
            #pragma unroll
            for (int p=0;p<4;p++)
                accX = __builtin_amdgcn_mfma_f32_16x16x32_bf16(afr[p], afr[p], accX, 0,0,0);
            if ((col>>2) == quad) s2_s[tt*16+col] = accX[col&3];
            if (col == 15){
                #pragma unroll
                for (int reg=0;reg<4;reg++) sm_s[tt*16+quad*4+reg] = acc[reg];
            }
        }
        if (jA < 28){
            #pragma unroll
            for (int reg=0;reg<4;reg++)
                praw[(tt*16+quad*4+reg)*28 + jA] = acc[reg];
        }
    }
    __syncthreads();

    if (t < TOKS*4){
        const int tok = t>>2, h = t&3;
        float mu = sm_s[tok]*(1.f/128.f);
        float var = s2_s[tok]*(1.f/128.f) - mu*mu;
        float rs = rsqrtf(var + 1e-5f);
        const float* pr = &praw[tok*28 + h*7];
        float P[7];
        #pragma unroll
        for (int u=0;u<7;u++)
            P[u] = fmaf(rs, pr[u] - mu*sero[h*7+u], sero[28 + h*7+u]);
        const float T0=P[0],T1=P[1],T2=P[2],T3=P[3],Pa=P[4],Pb=P[5],Pc=P[6];
        const float4 m0v = *(const float4*)&obs_m[tok][0];
        const float4 m1v = *(const float4*)&obs_m[tok][4];
        // scale folded with log2(e): softmax(s) computed via exp2(s*log2e) exactly
        const float scale = 0.17677669529663687f * 1.4426950408889634f;
        float d0 = fmaf(T0,m0v.x, fmaf(T1,m0v.y, fmaf(T2,m0v.z, fmaf(T3,m0v.w, Pa))));
        float d1 = fmaf(T0,m1v.x, fmaf(T1,m1v.y, fmaf(T2,m1v.z, fmaf(T3,m1v.w, Pa))));
        float s0 = fmaf(krs_s[tok][0], d0 - kmu_s[tok][0]*Pb, Pc) * scale;
        float s1 = fmaf(krs_s[tok][1], d1 - kmu_s[tok][1]*Pb, Pc) * scale;
        int msk0 = kmask_s[tok][0], msk1 = kmask_s[tok][1];
        float a0, a1;
        if (msk0 && msk1){
            a0=0.f; a1=0.f;
            if (h==0) U_bf[tok*168 + 148] = 0;
        } else {
            if (h==0) U_bf[tok*168 + 148] = 0x3F80;
            if (msk0)      { a0=0.f; a1=1.f; }
            else if (msk1) { a0=1.f; a1=0.f; }
            else {
                float mx = fmaxf(s0,s1);
                float e0 = __ocml_native_exp2_f32(s0-mx);
                float e1 = __ocml_native_exp2_f32(s1-mx);
                float inv = 1.f/(e0+e1);
                a0 = e0*inv; a1 = e1*inv;
            }
        }
        int cb = tok*168 + 128 + h*5;
        unsigned y01 = cvtpk_bf16(fmaf(a0, m0v.x, a1*m1v.x), fmaf(a0, m0v.y, a1*m1v.y));
        unsigned y23 = cvtpk_bf16(fmaf(a0, m0v.z, a1*m1v.z), fmaf(a0, m0v.w, a1*m1v.w));
        U_bf[cb+0] = (unsigned short)y01;
        U_bf[cb+1] = (unsigned short)(y01 >> 16);
        U_bf[cb+2] = (unsigned short)y23;
        U_bf[cb+3] = (unsigned short)(y23 >> 16);
        U_bf[cb+4] = f2bf(a0 + a1);
    }
    __syncthreads();

    {
        bf16x8 bfr[5];
        #pragma unroll
        for (int p=0;p<4;p++) bfr[p] = *(const bf16x8*)&pb[((2*32 + w*4 + p)*64 + l)*8];
        bfr[4] = *(const bf16x8*)&pb[4096 + (w*64 + l)*8];
        f32x4 acc[4];
        #pragma unroll
        for (int tt=0;tt<4;tt++) acc[tt] = (f32x4){0.f,0.f,0.f,0.f};
        #pragma unroll
        for (int p=0;p<5;p++){
            const int ko = p*32 + quad*8;
            #pragma unroll
            for (int tt=0;tt<4;tt++){
                bf16x8 a = *(const bf16x8*)&U_bf[(tt*16+col)*168 + ko];
                acc[tt] = __builtin_amdgcn_mfma_f32_16x16x32_bf16(a, bfr[p], acc[tt], 0,0,0);
            }
        }
        const float b0j = b0[jj];
        #pragma unroll
        for (int tt=0;tt<4;tt++){
            float vv[4];
            #pragma unroll
            for (int reg=0;reg<4;reg++){
                float v = acc[tt][reg] + b0j;
                vv[reg] = (v > 0.f) ? v : 0.01f*v;
            }
            unsigned p01 = cvtpk_bf16(vv[0], vv[1]);
            unsigned p23 = cvtpk_bf16(vv[2], vv[3]);
            int base = (tt*16 + quad*4)*136 + jj;
            H1_bf[base      ] = (unsigned short)p01;
            H1_bf[base + 136] = (unsigned short)(p01 >> 16);
            H1_bf[base + 272] = (unsigned short)p23;
            H1_bf[base + 408] = (unsigned short)(p23 >> 16);
        }
    }
    __syncthreads();

    {
        bf16x8 bfr[4];
        #pragma unroll
        for (int p=0;p<4;p++) bfr[p] = *(const bf16x8*)&pb[((3*32 + w*4 + p)*64 + l)*8];
        f32x4 acc[4];
        #pragma unroll
        for (int tt=0;tt<4;tt++) acc[tt] = (f32x4){0.f,0.f,0.f,0.f};
        #pragma unroll
        for (int p=0;p<4;p++){
            const int ko = p*32 + quad*8;
            #pragma unroll
            for (int tt=0;tt<4;tt++){
                bf16x8 a = *(const bf16x8*)&H1_bf[(tt*16+col)*136 + ko];
                acc[tt] = __builtin_amdgcn_mfma_f32_16x16x32_bf16(a, bfr[p], acc[tt], 0,0,0);
            }
        }
        const float b1j = b1[jj];
        #pragma unroll
        for (int tt=0;tt<4;tt++){
            float vv[4];
            #pragma unroll
            for (int reg=0;reg<4;reg++){
                float v = acc[tt][reg] + b1j;
                vv[reg] = (v > 0.f) ? v : 0.01f*v;
            }
            unsigned p01 = cvtpk_bf16(vv[0], vv[1]);
            unsigned p23 = cvtpk_bf16(vv[2], vv[3]);
            int base = (tt*16 + quad*4)*168 + jj;
            U_bf[base      ] = (unsigned short)p01;
            U_bf[base + 168] = (unsigned short)(p01 >> 16);
            U_bf[base + 336] = (unsigned short)p23;
            U_bf[base + 504] = (unsigned short)(p23 >> 16);
        }
    }
    __syncthreads();

    if (w < 4){
        f32x4 acc = {0.f,0.f,0.f,0.f};
        #pragma unroll
        for (int p=0;p<4;p++){
            bf16x8 a = *(const bf16x8*)&U_bf[(w*16+col)*168 + p*32 + quad*8];
            bf16x8 b = *(const bf16x8*)&pb[8192 + (p*64 + l)*8];
            acc = __builtin_amdgcn_mfma_f32_16x16x32_bf16(a, b, acc, 0, 0, 0);
        }
        if (col == 0){
            float fb = fcb[0];
            #pragma unroll
            for (int reg=0;reg<4;reg++)
                out[n0 + w*16 + quad*4 + reg] = acc[reg] + fb;
        }
    }
}

extern "C" void kernel_launch(void* const* d_in, const int* in_sizes, int n_in,
                              void* d_out, int out_size, void* d_ws, size_t ws_size,
                              hipStream_t stream) {
    const float* obs       = (const float*)d_in[0];
    const float* h0        = (const float*)d_in[1];
    const float* enc_air_w = (const float*)d_in[2];
    const float* enc_air_b = (const float*)d_in[3];
    const float* enc_m_w   = (const float*)d_in[4];
    const float* enc_m_b   = (const float*)d_in[5];
    const float* gru_wih   = (const float*)d_in[6];
    const float* gru_whh   = (const float*)d_in[7];
    const float* gru_bih   = (const float*)d_in[8];
    const float* gru_bhh   = (const float*)d_in[9];
    const float* qln_w     = (const float*)d_in[10];
    const float* qln_b     = (const float*)d_in[11];
    const float* kln_w     = (const float*)d_in[12];
    const float* kln_b     = (const float*)d_in[13];
    const float* attn_in_w = (const float*)d_in[14];
    const float* attn_in_b = (const float*)d_in[15];
    const float* attn_out_w= (const float*)d_in[16];
    const float* attn_out_b= (const float*)d_in[17];
    const float* mlp0_w    = (const float*)d_in[18];
    const float* mlp0_b    = (const float*)d_in[19];
    const float* mlp1_w    = (const float*)d_in[20];
    const float* mlp1_b    = (const float*)d_in[21];
    const float* fco_w     = (const float*)d_in[22];
    const float* fco_b     = (const float*)d_in[23];
    float* out = (float*)d_out;
    float* ws  = (float*)d_ws;
    unsigned short* air = (unsigned short*)(ws + WS_AIR);

    precompute_kernel<<<dim3(384), dim3(256), 0, stream>>>(
        enc_air_w, enc_air_b, enc_m_w, enc_m_b, gru_wih, gru_bih,
        qln_w, qln_b, kln_w, kln_b, attn_in_w, attn_in_b,
        attn_out_w, mlp0_w, mlp1_w, ws);

    pack_gru_kernel<<<dim3(256), dim3(256), 0, stream>>>(gru_whh, ws);
    pack2_kernel<<<dim3(27), dim3(256), 0, stream>>>(attn_out_w, attn_out_b, ws);
    pack3_kernel<<<dim3(24), dim3(256), 0, stream>>>(mlp0_w, fco_w, ws);

    gru_kernel<<<dim3(256), dim3(512), 0, stream>>>(
        obs, h0, gru_bhh, enc_air_b, ws, air, out);

    attnmlp_kernel<<<dim3(N_/TOKS), dim3(512), 0, stream>>>(
        obs, ws, mlp0_b, mlp1_b, fco_b, air, out);
}

// Round 9
// 222.660 us; speedup vs baseline: 1.0046x; 1.0046x over previous
//
#include <hip/hip_runtime.h>
#include <math.h>

#define B_   4096
#define S_   64
#define H_   128
#define N_   (B_*S_)

// ---- workspace float offsets ----
#define WS_WC    0        // [384][16]  combined obs->gi weights (padded f=16)
#define WS_BC    6144     // [384]      combined gi bias
#define WS_WAP   6528     // [128][16]  padded enc_air_w
#define WS_WQP   8576     // [128][128] wq * qln_w (fp32 copy)
#define WS_SQ    24960    // [128] row sums of wqp
#define WS_EQ    25088    // [128] wq@qln_b + bq
#define WS_KC    25216    // [128][4]  (wk*klnw)@enc_m_w
#define WS_EK1   25728    // [128] (wk*klnw)@enc_m_b
#define WS_SK    25856    // [128] rowsum(wk*klnw)
#define WS_EK2   25984    // [128] wk@kln_b + bk
#define WS_VC    26112    // [128][4]  wv@enc_m_w
#define WS_VB    26624    // [128] wv@enc_m_b + bv
#define WS_MV    26752    // [4] mean weights for keys_raw mean
#define WS_QQ    26756    // [16] 4x4 quadratic form for E[y^2]
#define WS_QLIN  26772    // [4]
#define WS_MBC   26776
#define WS_C0    26777
// packed bf16 region (shorts): GA[0..4095] (rows 0..27 + ones row 31), GC5[4096..8191],
// fcw-frag[8192..10239], mm=2 mlp0 @32768, mm=3 mlp1 @49152
#define WS_PB    27392
#define WS_WO2T  (WS_PB + 5120)   // fp32 [21][128] Wo2 transposed (shifted past fcw frag)
#define WS_SROW  (WS_PB + 7808)   // fp32 [28]
#define WS_EROW  (WS_PB + 7836)   // fp32 [28]  (contiguous after SROW)
#define WS_GB    60160    // gru packed bf16 B-frags: 65536 ushort (32768 floats)
#define WS_AIR   92928    // air_feat buffer: bf16 [N_][128] ushort
#define TOKS     64       // attnmlp tokens per block

typedef __attribute__((ext_vector_type(8))) short bf16x8;
typedef __attribute__((ext_vector_type(4))) float f32x4;

extern "C" __device__ float __ocml_native_exp2_f32(float);   // single v_exp_f32

__device__ __forceinline__ unsigned short f2bf(float f){   // RNE fp32->bf16
    union { float f; unsigned u; } v; v.f = f;
    unsigned r = v.u + 0x7FFF + ((v.u >> 16) & 1);
    return (unsigned short)(r >> 16);
}
__device__ __forceinline__ float bf2f(unsigned short u){
    union { unsigned u; float f; } v; v.u = ((unsigned)u) << 16;
    return v.f;
}
// RNE pack of 2 f32 -> 1 u32 of 2 bf16 (low = a, high = b); single VALU instr
__device__ __forceinline__ unsigned cvtpk_bf16(float a, float b){
    unsigned r;
    asm("v_cvt_pk_bf16_f32 %0, %1, %2" : "=v"(r) : "v"(a), "v"(b));
    return r;
}

#define KL_SCALE (-1.4426950408889634f)   // -log2(e): R/Z gates
#define KN_SCALE ( 2.8853900817779268f)   // 2*log2(e): N/G gates

// ---------------- precompute folded weights + mlp bf16 B-frags ----------------
__global__ void precompute_kernel(
    const float* __restrict__ enc_air_w, const float* __restrict__ enc_air_b,
    const float* __restrict__ enc_m_w,  const float* __restrict__ enc_m_b,
    const float* __restrict__ gru_wih,  const float* __restrict__ gru_bih,
    const float* __restrict__ qln_w, const float* __restrict__ qln_b,
    const float* __restrict__ kln_w, const float* __restrict__ kln_b,
    const float* __restrict__ attn_in_w, const float* __restrict__ attn_in_b,
    const float* __restrict__ attn_out_w,
    const float* __restrict__ mlp0_w, const float* __restrict__ mlp1_w,
    float* __restrict__ ws)
{
    int i = blockIdx.x*blockDim.x + threadIdx.x;
    if (i < 6144) {                       // Wc[o][f] = sum_k wih[o][k]*Wa[k][f]
        int o = i>>4, f = i&15; float a = 0.f;
        if (f < 15) for (int k=0;k<128;k++) a = fmaf(gru_wih[o*128+k], enc_air_w[k*15+f], a);
        ws[WS_WC+i] = a;
    } else if (i < 6528) {                // bc
        int o = i-6144; float a = gru_bih[o];
        for (int k=0;k<128;k++) a = fmaf(gru_wih[o*128+k], enc_air_b[k], a);
        ws[WS_BC+o] = a;
    } else if (i < 8576) {                // Wap padded
        int idx = i-6528; int j = idx>>4, f = idx&15;
        ws[WS_WAP+idx] = (f<15) ? enc_air_w[j*15+f] : 0.f;
    } else if (i < 24960) {               // wqp (fp32 copy)
        int idx = i-8576; int o = idx>>7, j = idx&127;
        ws[WS_WQP+idx] = attn_in_w[o*128+j]*qln_w[j];
    } else if (i < 25088) {               // sq
        int o = i-24960; float a=0.f;
        for (int j=0;j<128;j++) a = fmaf(attn_in_w[o*128+j], qln_w[j], a);
        ws[WS_SQ+o]=a;
    } else if (i < 25216) {               // eq
        int o = i-25088; float a = attn_in_b[o];
        for (int j=0;j<128;j++) a = fmaf(attn_in_w[o*128+j], qln_b[j], a);
        ws[WS_EQ+o]=a;
    } else if (i < 25728) {               // Kc
        int idx = i-25216; int o = idx>>2, f = idx&3; float a=0.f;
        for (int j=0;j<128;j++) a = fmaf(attn_in_w[(128+o)*128+j]*kln_w[j], enc_m_w[j*4+f], a);
        ws[WS_KC+idx]=a;
    } else if (i < 25856) {               // ek1
        int o = i-25728; float a=0.f;
        for (int j=0;j<128;j++) a = fmaf(attn_in_w[(128+o)*128+j]*kln_w[j], enc_m_b[j], a);
        ws[WS_EK1+o]=a;
    } else if (i < 25984) {               // sk
        int o = i-25856; float a=0.f;
        for (int j=0;j<128;j++) a = fmaf(attn_in_w[(128+o)*128+j], kln_w[j], a);
        ws[WS_SK+o]=a;
    } else if (i < 26112) {               // ek2
        int o = i-25984; float a = attn_in_b[128+o];
        for (int j=0;j<128;j++) a = fmaf(attn_in_w[(128+o)*128+j], kln_b[j], a);
        ws[WS_EK2+o]=a;
    } else if (i < 26624) {               // Vc
        int idx = i-26112; int o = idx>>2, f = idx&3; float a=0.f;
        for (int j=0;j<128;j++) a = fmaf(attn_in_w[(256+o)*128+j], enc_m_w[j*4+f], a);
        ws[WS_VC+idx]=a;
    } else if (i < 26752) {               // vb
        int o = i-26624; float a = attn_in_b[256+o];
        for (int j=0;j<128;j++) a = fmaf(attn_in_w[(256+o)*128+j], enc_m_b[j], a);
        ws[WS_VB+o]=a;
    } else if (i < 26756) {               // Mv
        int f = i-26752; float a=0.f;
        for (int j=0;j<128;j++) a += enc_m_w[j*4+f];
        ws[WS_MV+f]=a*(1.f/128.f);
    } else if (i < 26772) {               // QQ
        int idx = i-26756; int a4 = idx>>2, b4 = idx&3; float a=0.f;
        for (int j=0;j<128;j++) a = fmaf(enc_m_w[j*4+a4], enc_m_w[j*4+b4], a);
        ws[WS_QQ+idx]=a*(1.f/128.f);
    } else if (i < 26776) {               // qlin
        int f = i-26772; float a=0.f;
        for (int j=0;j<128;j++) a = fmaf(enc_m_b[j], enc_m_w[j*4+f], a);
        ws[WS_QLIN+f]=a*(2.f/128.f);
    } else if (i == 26776) {
        float a=0.f; for (int j=0;j<128;j++) a += enc_m_b[j];
        ws[WS_MBC]=a*(1.f/128.f);
    } else if (i == 26777) {
        float a=0.f; for (int j=0;j<128;j++) a = fmaf(enc_m_b[j], enc_m_b[j], a);
        ws[WS_C0]=a*(1.f/128.f);
    } else if (i >= 32768 && i < 98304) {
        // mlp bf16 B-frags (mm=2: mlp0, mm=3: mlp1)
        int idx = i - 32768;              // 0..65535
        int mm = idx>>14;
        if (mm >= 2) {
            int i8 = idx & 7, l = (idx>>3)&63, p = (idx>>9)&3, wv = (idx>>11)&7;
            int n = 16*wv + (l&15);
            int k = 32*p + ((l>>4)<<3) + i8;
            float v = (mm==2) ? mlp0_w[n*128+k] : mlp1_w[n*128+k];
            ((unsigned short*)(ws+WS_PB))[idx] = f2bf(v);
        }
    }
}

// ---------------- pack GRU bf16 B-frags (gate-scaled for exp2 finalize) ----------
__global__ void pack_gru_kernel(const float* __restrict__ whh, float* __restrict__ ws)
{
    int idx = blockIdx.x*blockDim.x + threadIdx.x;   // [0, 65536)
    int i8 = idx&7, l=(idx>>3)&63, w=(idx>>9)&7, f=idx>>12;
    int n = 16*w + (l&15);
    int k = ((l>>4)<<3) + i8;       // 0..31 within chunk
    float v = 0.f;
    if (f < 5) {
        int kk = f*32 + k;
        if (kk < 128) v = whh[n*128 + kk];
        else { int kl = kk-128; if (kl<16) v = ws[WS_WC + n*16 + kl]; }
        v *= KL_SCALE;
    } else if (f < 10) {
        int kk = (f-5)*32 + k;
        if (kk < 128) v = whh[(128+n)*128 + kk];
        else { int kl = kk-128; if (kl<16) v = ws[WS_WC + (128+n)*16 + kl]; }
        v *= KL_SCALE;
    } else if (f < 14) {
        int kk = (f-10)*32 + k;
        v = whh[(256+n)*128 + kk] * KN_SCALE;
    } else if (f == 14) {
        if (k < 16) v = ws[WS_WC + (256+n)*16 + k] * KN_SCALE;
    } else {
        if (k < 16) v = ws[WS_WAP + n*16 + k];
    }
    ((unsigned short*)(ws+WS_GB))[idx] = f2bf(v);
}

// ---------------- pack2: GA (score projections + ones-row), Srow/Erow, Wo2T ------
__global__ void pack2_kernel(const float* __restrict__ wo, const float* __restrict__ bo,
                             float* __restrict__ ws)
{
    int i = blockIdx.x*blockDim.x + threadIdx.x;   // 27*256 = 6912
    if (i < 4096) {                                // GA packed bf16 (2 col-tiles x 4 ksteps)
        int i8=i&7, l=(i>>3)&63, p=(i>>9)&3, ct=(i>>11)&1;
        int r = 16*ct + (l&15);
        int k = 32*p + ((l>>4)<<3) + i8;
        float v = 0.f;
        if (r < 28){
            int h = r/7, u = r - h*7;
            float a = 0.f;
            for (int d5=0; d5<32; d5++){
                int d = h*32 + d5;
                float c = (u<4) ? ws[WS_KC + d*4 + u]
                        : (u==4) ? ws[WS_EK1 + d]
                        : (u==5) ? ws[WS_SK + d]
                        :          ws[WS_EK2 + d];
                a = fmaf(c, ws[WS_WQP + d*128 + k], a);
            }
            v = a;
        } else if (r == 31) {
            v = 1.f;                               // ones-row: GEMM A col 31 = sum(X)
        }
        ((unsigned short*)(ws+WS_PB))[i] = f2bf(v);
    } else if (i < 4152) {                         // Srow / Erow
        int j = i - 4096; int r = j % 28; int era = j / 28;
        int h = r/7, u = r - h*7;
        float a = 0.f;
        for (int d5=0; d5<32; d5++){
            int d = h*32 + d5;
            float c = (u<4) ? ws[WS_KC + d*4 + u]
                    : (u==4) ? ws[WS_EK1 + d]
                    : (u==5) ? ws[WS_SK + d]
                    :          ws[WS_EK2 + d];
            a = fmaf(c, ws[(era ? WS_EQ : WS_SQ) + d], a);
        }
        ws[(era ? WS_EROW : WS_SROW) + r] = a;
    } else if (i >= 4224 && i < 6912) {            // Wo2T[c][o]; c=20 -> bo
        int j = i - 4224; int c = j>>7, o = j&127;
        float a;
        if (c == 20) a = bo[o];
        else {
            int h = c/5, u = c - h*5;
            a = 0.f;
            for (int d5=0; d5<32; d5++){
                int d = h*32 + d5;
                float cv = (u<4) ? ws[WS_VC + d*4 + u] : ws[WS_VB + d];
                a = fmaf(wo[o*128 + d], cv, a);
            }
        }
        ws[WS_WO2T + c*128 + o] = a;
    }
}

// ---------------- pack3: GC5 = mlp0_w @ Wo2 + fcw B-frag ----------------
__global__ void pack3_kernel(const float* __restrict__ mlp0_w,
                             const float* __restrict__ fcw,
                             float* __restrict__ ws)
{
    int i = blockIdx.x*blockDim.x + threadIdx.x;   // 24 blocks x 256 = 6144
    if (i < 4096){
        int i8=i&7, l=(i>>3)&63, w=(i>>9)&7;
        int n = 16*w + (l&15);
        int c = ((l>>4)<<3) + i8;                  // 0..31 (cols 128..159 of Wc)
        float v = 0.f;
        if (c < 21){
            float a = 0.f;
            const float* wo2 = ws + WS_WO2T + c*128;
            for (int o=0;o<128;o++) a = fmaf(mlp0_w[n*128+o], wo2[o], a);
            v = a;
        }
        ((unsigned short*)(ws+WS_PB))[4096 + i] = f2bf(v);
    } else {
        // fcw B-frag: col 0 = fcw[k], other cols 0.  2048 shorts at pb[8192..]
        int j = i - 4096;                          // 0..2047
        int i8=j&7, l=(j>>3)&63, p=(j>>9)&3;
        int k = 32*p + ((l>>4)<<3) + i8;
        float v = ((l&15)==0) ? fcw[k] : 0.f;
        ((unsigned short*)(ws+WS_PB))[8192 + j] = f2bf(v);
    }
}

// ---------------- Kernel A v9: GRU — R7 step body (4-deep chains) restored -------
__global__ __launch_bounds__(512) void gru_kernel(
    const float* __restrict__ obs, const float* __restrict__ h0,
    const float* __restrict__ bhh, const float* __restrict__ ba,
    const float* __restrict__ ws,
    unsigned short* __restrict__ air, float* __restrict__ out)
{
    __shared__ __align__(16) unsigned short Abf[2][16*136];      // h bf16, pitch 136
    __shared__ __align__(16) unsigned short obs_lds[64*16*24];   // [s][tok][24] bf16
    __shared__ __align__(16) unsigned short zero16[8];

    const int t = threadIdx.x;
    const int w = t>>6;          // wave 0..7
    const int l = t&63;
    const int quad = l>>4;
    const int col  = l&15;
    const int jj   = 16*w + col; // output column j
    const int row0 = blockIdx.x*16;

    const unsigned short* gb = (const unsigned short*)(ws + WS_GB);
    bf16x8 bf[16];
    #pragma unroll
    for (int f=0; f<16; f++) bf[f] = *(const bf16x8*)&gb[(f*8 + w)*512 + l*8];

    // scaled biases -> loop-invariant MFMA C-operand splats
    const float bcrt = KL_SCALE*(ws[WS_BC+jj]     + bhh[jj]);
    const float bczt = KL_SCALE*(ws[WS_BC+128+jj] + bhh[128+jj]);
    const float bcn  = KN_SCALE*ws[WS_BC+256+jj];
    const float bhn  = KN_SCALE*bhh[256+jj];
    const float baj  = ba[jj];
    const f32x4 cR = {bcrt,bcrt,bcrt,bcrt};
    const f32x4 cZ = {bczt,bczt,bczt,bczt};
    const f32x4 cG = {bcn,bcn,bcn,bcn};
    const f32x4 cE = {baj,baj,baj,baj};
    const f32x4 cN = {bhn,bhn,bhn,bhn};

    float hreg[4];
    #pragma unroll
    for (int reg=0; reg<4; reg++)
        hreg[reg] = h0[(size_t)(row0+quad*4+reg)*128 + jj];

    if (t < 8) zero16[t] = 0;

    {
        int rr = t>>5, c0i = (t&31)*4;
        float4 hv = *(const float4*)&h0[(size_t)(row0+rr)*128 + c0i];
        unsigned lo = cvtpk_bf16(hv.x, hv.y);
        unsigned hi = cvtpk_bf16(hv.z, hv.w);
        unsigned long long pk = (unsigned long long)lo | ((unsigned long long)hi << 32);
        *(unsigned long long*)&Abf[0][rr*136 + c0i] = pk;
    }

    #pragma unroll
    for (int it=0; it<8; it++){
        int pair = it*128 + (t>>2);      // (tok,s) pair, 4 lanes each
        int sub  = t&3;
        int tok = pair>>6, s = pair&63;
        const float* op = &obs[((size_t)(row0+tok)*64 + s)*15 + sub*4];
        float o0 = op[0];
        float o1 = (sub*4+1<15) ? op[1] : 0.f;
        float o2 = (sub*4+2<15) ? op[2] : 0.f;
        float o3 = (sub*4+3<15) ? op[3] : 0.f;
        unsigned lo = cvtpk_bf16(o0, o1);
        unsigned hi = cvtpk_bf16(o2, o3);
        unsigned long long pk = (unsigned long long)lo | ((unsigned long long)hi << 32);
        *(unsigned long long*)&obs_lds[(s*16+tok)*24 + sub*4] = pk;
    }
    __syncthreads();

    // per-reg air pointers (reg offsets exceed the 13-bit store immediate)
    unsigned short* ap0 = air + (size_t)(row0 + quad*4 + 0)*8192 + jj;
    unsigned short* ap1 = air + (size_t)(row0 + quad*4 + 1)*8192 + jj;
    unsigned short* ap2 = air + (size_t)(row0 + quad*4 + 2)*8192 + jj;
    unsigned short* ap3 = air + (size_t)(row0 + quad*4 + 3)*8192 + jj;
    const int anb = (quad*4)*136 + jj;   // An short-index base (rows +136)

    // prologue: obs-only MFMA accs for step 0 (biases ride in C)
    f32x4 oR, oZ, oG, oE;
    {
        const unsigned short* osrc = (quad<2)
            ? &obs_lds[(0*16+col)*24 + quad*8] : &zero16[0];
        bf16x8 a4 = *(const bf16x8*)osrc;
        oR = __builtin_amdgcn_mfma_f32_16x16x32_bf16(a4, bf[4],  cR, 0,0,0);
        oZ = __builtin_amdgcn_mfma_f32_16x16x32_bf16(a4, bf[9],  cZ, 0,0,0);
        oG = __builtin_amdgcn_mfma_f32_16x16x32_bf16(a4, bf[14], cG, 0,0,0);
        oE = __builtin_amdgcn_mfma_f32_16x16x32_bf16(a4, bf[15], cE, 0,0,0);
    }

    unsigned short* const A0 = &Abf[0][0];
    unsigned short* const A1 = &Abf[1][0];

// R7 body: single 4-deep accumulate chains; OFF = air store offset (0 or 128)
#define GRU_STEP(S, AC, AN, OFF)                                                   \
    {                                                                              \
        bf16x8 a0 = *(const bf16x8*)&(AC)[col*136 +  0 + quad*8];                  \
        bf16x8 a1 = *(const bf16x8*)&(AC)[col*136 + 32 + quad*8];                  \
        bf16x8 a2 = *(const bf16x8*)&(AC)[col*136 + 64 + quad*8];                  \
        bf16x8 a3 = *(const bf16x8*)&(AC)[col*136 + 96 + quad*8];                  \
        f32x4 aR = oR, aZ = oZ;                                                    \
        f32x4 aN = cN;                                                             \
        aR = __builtin_amdgcn_mfma_f32_16x16x32_bf16(a0, bf[0],  aR, 0,0,0);       \
        aR = __builtin_amdgcn_mfma_f32_16x16x32_bf16(a1, bf[1],  aR, 0,0,0);       \
        aR = __builtin_amdgcn_mfma_f32_16x16x32_bf16(a2, bf[2],  aR, 0,0,0);       \
        aR = __builtin_amdgcn_mfma_f32_16x16x32_bf16(a3, bf[3],  aR, 0,0,0);       \
        aZ = __builtin_amdgcn_mfma_f32_16x16x32_bf16(a0, bf[5],  aZ, 0,0,0);       \
        aZ = __builtin_amdgcn_mfma_f32_16x16x32_bf16(a1, bf[6],  aZ, 0,0,0);       \
        aZ = __builtin_amdgcn_mfma_f32_16x16x32_bf16(a2, bf[7],  aZ, 0,0,0);       \
        aZ = __builtin_amdgcn_mfma_f32_16x16x32_bf16(a3, bf[8],  aZ, 0,0,0);       \
        aN = __builtin_amdgcn_mfma_f32_16x16x32_bf16(a0, bf[10], aN, 0,0,0);       \
        aN = __builtin_amdgcn_mfma_f32_16x16x32_bf16(a1, bf[11], aN, 0,0,0);       \
        aN = __builtin_amdgcn_mfma_f32_16x16x32_bf16(a2, bf[12], aN, 0,0,0);       \
        aN = __builtin_amdgcn_mfma_f32_16x16x32_bf16(a3, bf[13], aN, 0,0,0);       \
        f32x4 nR, nZ, nG, nE;                                                      \
        if ((S) < 63){                                                             \
            const unsigned short* osrc = (quad<2)                                  \
                ? &obs_lds[(((S)+1)*16+col)*24 + quad*8] : &zero16[0];             \
            bf16x8 a4 = *(const bf16x8*)osrc;                                      \
            nR = __builtin_amdgcn_mfma_f32_16x16x32_bf16(a4, bf[4],  cR, 0,0,0);   \
            nZ = __builtin_amdgcn_mfma_f32_16x16x32_bf16(a4, bf[9],  cZ, 0,0,0);   \
            nG = __builtin_amdgcn_mfma_f32_16x16x32_bf16(a4, bf[14], cG, 0,0,0);   \
            nE = __builtin_amdgcn_mfma_f32_16x16x32_bf16(a4, bf[15], cE, 0,0,0);   \
        }                                                                          \
        float hnv[4], avv[4];                                                      \
        _Pragma("unroll")                                                          \
        for (int reg=0; reg<4; reg++){                                             \
            float rg = __builtin_amdgcn_rcpf(1.f + __ocml_native_exp2_f32(aR[reg]));\
            float zg = __builtin_amdgcn_rcpf(1.f + __ocml_native_exp2_f32(aZ[reg]));\
            float nx = fmaf(rg, aN[reg], oG[reg]);                                 \
            float e2 = __ocml_native_exp2_f32(nx);                                 \
            float ng = 1.f - 2.f*__builtin_amdgcn_rcpf(e2 + 1.f);                  \
            float hn = fmaf(zg, hreg[reg]-ng, ng);                                 \
            hreg[reg] = hn;                                                        \
            hnv[reg] = hn;                                                         \
            avv[reg] = hn + oE[reg];                                               \
        }                                                                          \
        unsigned ph01 = cvtpk_bf16(hnv[0], hnv[1]);                                \
        unsigned ph23 = cvtpk_bf16(hnv[2], hnv[3]);                                \
        unsigned pa01 = cvtpk_bf16(avv[0], avv[1]);                                \
        unsigned pa23 = cvtpk_bf16(avv[2], avv[3]);                                \
        (AN)[anb        ] = (unsigned short)ph01;                                  \
        (AN)[anb + 136  ] = (unsigned short)(ph01 >> 16);                          \
        (AN)[anb + 272  ] = (unsigned short)ph23;                                  \
        (AN)[anb + 408  ] = (unsigned short)(ph23 >> 16);                          \
        ap0[OFF] = (unsigned short)pa01;  ap1[OFF] = (unsigned short)(pa01 >> 16); \
        ap2[OFF] = (unsigned short)pa23;  ap3[OFF] = (unsigned short)(pa23 >> 16); \
        if ((S) < 63){ oR = nR; oZ = nZ; oG = nG; oE = nE; }                       \
        asm volatile("s_waitcnt lgkmcnt(0)" ::: "memory");                         \
        __builtin_amdgcn_s_barrier();                                              \
        __builtin_amdgcn_sched_barrier(0);                                         \
    }

    for (int s = 0; s < 64; s += 2){
        GRU_STEP(s,   A0, A1, 0)
        GRU_STEP(s+1, A1, A0, 128)
        ap0 += 256; ap1 += 256; ap2 += 256; ap3 += 256;
    }
#undef GRU_STEP

    #pragma unroll
    for (int reg=0; reg<4; reg++)
        out[(size_t)N_ + (size_t)(row0+quad*4+reg)*128 + jj] = hreg[reg];
}

// ---------------- Kernel B v6: attn+MLP (exp2 softmax, cvt_pk epilogues) ----------
__global__ __launch_bounds__(512) void attnmlp_kernel(
    const float* __restrict__ obs,
    const float* __restrict__ ws,
    const float* __restrict__ b0, const float* __restrict__ b1,
    const float* __restrict__ fcb,
    const unsigned short* __restrict__ air, float* __restrict__ out)
{
    __shared__ __align__(16) unsigned short U_bf[TOKS*168];
    __shared__ __align__(16) unsigned short H1_bf[TOKS*136];
    __shared__ float praw[TOKS*28];
    __shared__ float obs_m[TOKS][8];
    __shared__ float sm_s[TOKS], s2_s[TOKS];
    __shared__ float kmu_s[TOKS][2], krs_s[TOKS][2];
    __shared__ int   kmask_s[TOKS][2];
    __shared__ float sero[56];

    const int t = threadIdx.x;
    const int w = t>>6;
    const int l = t&63;
    const int quad = l>>4;
    const int col  = l&15;
    const int jj   = 16*w + col;
    const int n0 = blockIdx.x*TOKS;

    const unsigned short* pb = (const unsigned short*)(ws + WS_PB);

    {
        const int tok0 = t>>3, sub = t&7;
        const unsigned short* apx = &air[(size_t)(n0+tok0)*128 + sub*16];
        uint4 x0 = *(const uint4*)apx;
        uint4 x1 = *(const uint4*)(apx+8);
        *(uint4*)&U_bf[tok0*168 + sub*16]     = x0;
        *(uint4*)&U_bf[tok0*168 + sub*16 + 8] = x1;
        if (sub < 5){
            #pragma unroll
            for (int c=0;c<4;c++) U_bf[tok0*168 + 148 + sub*4 + c] = 0;
        }
        obs_m[tok0][sub] = obs[(size_t)(n0+tok0)*15 + sub];
    }
    if (t < 128){
        int rr = t>>1, mi = t&1;
        const float* mp = &obs[(size_t)(n0+rr)*15 + mi*4];
        float m0=mp[0], m1=mp[1], m2=mp[2], m3=mp[3];
        const float tol1 = 1e-8f + 1e-5f, tol0 = 1e-8f;
        kmask_s[rr][mi] = (fabsf(m0-1.f)<=tol1)&&(fabsf(m1)<=tol0)&&
                          (fabsf(m2-1.f)<=tol1)&&(fabsf(m3)<=tol0);
        float mv[4]={m0,m1,m2,m3};
        float mu = ws[WS_MBC];
        #pragma unroll
        for (int f=0;f<4;f++) mu = fmaf(ws[WS_MV+f], mv[f], mu);
        float e2 = ws[WS_C0];
        #pragma unroll
        for (int a4=0;a4<4;a4++){
            e2 = fmaf(ws[WS_QLIN+a4], mv[a4], e2);
            #pragma unroll
            for (int b4=0;b4<4;b4++) e2 = fmaf(ws[WS_QQ+a4*4+b4]*mv[a4], mv[b4], e2);
        }
        float var = e2 - mu*mu;
        kmu_s[rr][mi]=mu; krs_s[rr][mi]=rsqrtf(var+1e-5f);
    }
    if (t < 56) sero[t] = ws[WS_SROW + t];
    __syncthreads();

    {
        const int tt = w>>1, ct = w&1;
        const int jA = ct*16 + col;
        bf16x8 afr[4];
        #pragma unroll
        for (int p=0;p<4;p++)
            afr[p] = *(const bf16x8*)&U_bf[(tt*16+col)*168 + p*32 + quad*8];
        f32x4 acc = {0.f,0.f,0.f,0.f};
        #pragma unroll
        for (int p=0;p<4;p++)
            acc = __builtin_amdgcn_mfma_f32_16x16x32_bf16(afr[p], *(const bf16x8*)&pb[((ct*4+p)*64 + l)*8], acc, 0,0,0);
        if (ct == 1){
            f32x4 accX = {0.f,0.f,0.f,0.f};
            #pragma unroll
            for (int p=0;p<4;p++)
                accX = __builtin_amdgcn_mfma_f32_16x16x32_bf16(afr[p], afr[p], accX, 0,0,0);
            if ((col>>2) == quad) s2_s[tt*16+col] = accX[col&3];
            if (col == 15){
                #pragma unroll
                for (int reg=0;reg<4;reg++) sm_s[tt*16+quad*4+reg] = acc[reg];
            }
        }
        if (jA < 28){
            #pragma unroll
            for (int reg=0;reg<4;reg++)
                praw[(tt*16+quad*4+reg)*28 + jA] = acc[reg];
        }
    }
    __syncthreads();

    if (t < TOKS*4){
        const int tok = t>>2, h = t&3;
        float mu = sm_s[tok]*(1.f/128.f);
        float var = s2_s[tok]*(1.f/128.f) - mu*mu;
        float rs = rsqrtf(var + 1e-5f);
        const float* pr = &praw[tok*28 + h*7];
        float P[7];
        #pragma unroll
        for (int u=0;u<7;u++)
            P[u] = fmaf(rs, pr[u] - mu*sero[h*7+u], sero[28 + h*7+u]);
        const float T0=P[0],T1=P[1],T2=P[2],T3=P[3],Pa=P[4],Pb=P[5],Pc=P[6];
        const float4 m0v = *(const float4*)&obs_m[tok][0];
        const float4 m1v = *(const float4*)&obs_m[tok][4];
        // scale folded with log2(e): softmax(s) via exp2 — exact identity
        const float scale = 0.17677669529663687f * 1.4426950408889634f;
        float d0 = fmaf(T0,m0v.x, fmaf(T1,m0v.y, fmaf(T2,m0v.z, fmaf(T3,m0v.w, Pa))));
        float d1 = fmaf(T0,m1v.x, fmaf(T1,m1v.y, fmaf(T2,m1v.z, fmaf(T3,m1v.w, Pa))));
        float s0 = fmaf(krs_s[tok][0], d0 - kmu_s[tok][0]*Pb, Pc) * scale;
        float s1 = fmaf(krs_s[tok][1], d1 - kmu_s[tok][1]*Pb, Pc) * scale;
        int msk0 = kmask_s[tok][0], msk1 = kmask_s[tok][1];
        float a0, a1;
        if (msk0 && msk1){
            a0=0.f; a1=0.f;
            if (h==0) U_bf[tok*168 + 148] = 0;
        } else {
            if (h==0) U_bf[tok*168 + 148] = 0x3F80;
            if (msk0)      { a0=0.f; a1=1.f; }
            else if (msk1) { a0=1.f; a1=0.f; }
            else {
                float mx = fmaxf(s0,s1);
                float e0 = __ocml_native_exp2_f32(s0-mx);
                float e1 = __ocml_native_exp2_f32(s1-mx);
                float inv = 1.f/(e0+e1);
                a0 = e0*inv; a1 = e1*inv;
            }
        }
        int cb = tok*168 + 128 + h*5;
        unsigned y01 = cvtpk_bf16(fmaf(a0, m0v.x, a1*m1v.x), fmaf(a0, m0v.y, a1*m1v.y));
        unsigned y23 = cvtpk_bf16(fmaf(a0, m0v.z, a1*m1v.z), fmaf(a0, m0v.w, a1*m1v.w));
        U_bf[cb+0] = (unsigned short)y01;
        U_bf[cb+1] = (unsigned short)(y01 >> 16);
        U_bf[cb+2] = (unsigned short)y23;
        U_bf[cb+3] = (unsigned short)(y23 >> 16);
        U_bf[cb+4] = f2bf(a0 + a1);
    }
    __syncthreads();

    {
        bf16x8 bfr[5];
        #pragma unroll
        for (int p=0;p<4;p++) bfr[p] = *(const bf16x8*)&pb[((2*32 + w*4 + p)*64 + l)*8];
        bfr[4] = *(const bf16x8*)&pb[4096 + (w*64 + l)*8];
        f32x4 acc[4];
        #pragma unroll
        for (int tt=0;tt<4;tt++) acc[tt] = (f32x4){0.f,0.f,0.f,0.f};
        #pragma unroll
        for (int p=0;p<5;p++){
            const int ko = p*32 + quad*8;
            #pragma unroll
            for (int tt=0;tt<4;tt++){
                bf16x8 a = *(const bf16x8*)&U_bf[(tt*16+col)*168 + ko];
                acc[tt] = __builtin_amdgcn_mfma_f32_16x16x32_bf16(a, bfr[p], acc[tt], 0,0,0);
            }
        }
        const float b0j = b0[jj];
        #pragma unroll
        for (int tt=0;tt<4;tt++){
            float vv[4];
            #pragma unroll
            for (int reg=0;reg<4;reg++){
                float v = acc[tt][reg] + b0j;
                vv[reg] = (v > 0.f) ? v : 0.01f*v;
            }
            unsigned p01 = cvtpk_bf16(vv[0], vv[1]);
            unsigned p23 = cvtpk_bf16(vv[2], vv[3]);
            int base = (tt*16 + quad*4)*136 + jj;
            H1_bf[base      ] = (unsigned short)p01;
            H1_bf[base + 136] = (unsigned short)(p01 >> 16);
            H1_bf[base + 272] = (unsigned short)p23;
            H1_bf[base + 408] = (unsigned short)(p23 >> 16);
        }
    }
    __syncthreads();

    {
        bf16x8 bfr[4];
        #pragma unroll
        for (int p=0;p<4;p++) bfr[p] = *(const bf16x8*)&pb[((3*32 + w*4 + p)*64 + l)*8];
        f32x4 acc[4];
        #pragma unroll
        for (int tt=0;tt<4;tt++) acc[tt] = (f32x4){0.f,0.f,0.f,0.f};
        #pragma unroll
        for (int p=0;p<4;p++){
            const int ko = p*32 + quad*8;
            #pragma unroll
            for (int tt=0;tt<4;tt++){
                bf16x8 a = *(const bf16x8*)&H1_bf[(tt*16+col)*136 + ko];
                acc[tt] = __builtin_amdgcn_mfma_f32_16x16x32_bf16(a, bfr[p], acc[tt], 0,0,0);
            }
        }
        const float b1j = b1[jj];
        #pragma unroll
        for (int tt=0;tt<4;tt++){
            float vv[4];
            #pragma unroll
            for (int reg=0;reg<4;reg++){
                float v = acc[tt][reg] + b1j;
                vv[reg] = (v > 0.f) ? v : 0.01f*v;
            }
            unsigned p01 = cvtpk_bf16(vv[0], vv[1]);
            unsigned p23 = cvtpk_bf16(vv[2], vv[3]);
            int base = (tt*16 + quad*4)*168 + jj;
            U_bf[base      ] = (unsigned short)p01;
            U_bf[base + 168] = (unsigned short)(p01 >> 16);
            U_bf[base + 336] = (unsigned short)p23;
            U_bf[base + 504] = (unsigned short)(p23 >> 16);
        }
    }
    __syncthreads();

    if (w < 4){
        f32x4 acc = {0.f,0.f,0.f,0.f};
        #pragma unroll
        for (int p=0;p<4;p++){
            bf16x8 a = *(const bf16x8*)&U_bf[(w*16+col)*168 + p*32 + quad*8];
            bf16x8 b = *(const bf16x8*)&pb[8192 + (p*64 + l)*8];
            acc = __builtin_amdgcn_mfma_f32_16x16x32_bf16(a, b, acc, 0, 0, 0);
        }
        if (col == 0){
            float fb = fcb[0];
            #pragma unroll
            for (int reg=0;reg<4;reg++)
                out[n0 + w*16 + quad*4 + reg] = acc[reg] + fb;
        }
    }
}

extern "C" void kernel_launch(void* const* d_in, const int* in_sizes, int n_in,
                              void* d_out, int out_size, void* d_ws, size_t ws_size,
                              hipStream_t stream) {
    const float* obs       = (const float*)d_in[0];
    const float* h0        = (const float*)d_in[1];
    const float* enc_air_w = (const float*)d_in[2];
    const float* enc_air_b = (const float*)d_in[3];
    const float* enc_m_w   = (const float*)d_in[4];
    const float* enc_m_b   = (const float*)d_in[5];
    const float* gru_wih   = (const float*)d_in[6];
    const float* gru_whh   = (const float*)d_in[7];
    const float* gru_bih   = (const float*)d_in[8];
    const float* gru_bhh   = (const float*)d_in[9];
    const float* qln_w     = (const float*)d_in[10];
    const float* qln_b     = (const float*)d_in[11];
    const float* kln_w     = (const float*)d_in[12];
    const float* kln_b     = (const float*)d_in[13];
    const float* attn_in_w = (const float*)d_in[14];
    const float* attn_in_b = (const float*)d_in[15];
    const float* attn_out_w= (const float*)d_in[16];
    const float* attn_out_b= (const float*)d_in[17];
    const float* mlp0_w    = (const float*)d_in[18];
    const float* mlp0_b    = (const float*)d_in[19];
    const float* mlp1_w    = (const float*)d_in[20];
    const float* mlp1_b    = (const float*)d_in[21];
    const float* fco_w     = (const float*)d_in[22];
    const float* fco_b     = (const float*)d_in[23];
    float* out = (float*)d_out;
    float* ws  = (float*)d_ws;
    unsigned short* air = (unsigned short*)(ws + WS_AIR);

    precompute_kernel<<<dim3(384), dim3(256), 0, stream>>>(
        enc_air_w, enc_air_b, enc_m_w, enc_m_b, gru_wih, gru_bih,
        qln_w, qln_b, kln_w, kln_b, attn_in_w, attn_in_b,
        attn_out_w, mlp0_w, mlp1_w, ws);

    pack_gru_kernel<<<dim3(256), dim3(256), 0, stream>>>(gru_whh, ws);
    pack2_kernel<<<dim3(27), dim3(256), 0, stream>>>(attn_out_w, attn_out_b, ws);
    pack3_kernel<<<dim3(24), dim3(256), 0, stream>>>(mlp0_w, fco_w, ws);

    gru_kernel<<<dim3(256), dim3(512), 0, stream>>>(
        obs, h0, gru_bhh, enc_air_b, ws, air, out);

    attnmlp_kernel<<<dim3(N_/TOKS), dim3(512), 0, stream>>>(
        obs, ws, mlp0_b, mlp1_b, fco_b, air, out);
}

// Round 10
// 219.176 us; speedup vs baseline: 1.0206x; 1.0159x over previous
//
#include <hip/hip_runtime.h>
#include <math.h>

#define B_   4096
#define S_   64
#define H_   128
#define N_   (B_*S_)

// ---- workspace float offsets ----
#define WS_BC    6144     // [384]      combined gi bias (WC/WAP sections deleted — inlined into GB pack)
#define WS_WQP   8576     // [128][128] wq * qln_w (fp32 copy)
#define WS_SQ    24960    // [128] row sums of wqp
#define WS_EQ    25088    // [128] wq@qln_b + bq
#define WS_KC    25216    // [128][4]  (wk*klnw)@enc_m_w
#define WS_EK1   25728    // [128] (wk*klnw)@enc_m_b
#define WS_SK    25856    // [128] rowsum(wk*klnw)
#define WS_EK2   25984    // [128] wk@kln_b + bk
#define WS_VC    26112    // [128][4]  wv@enc_m_w
#define WS_VB    26624    // [128] wv@enc_m_b + bv
#define WS_MV    26752    // [4] mean weights for keys_raw mean
#define WS_QQ    26756    // [16] 4x4 quadratic form for E[y^2]
#define WS_QLIN  26772    // [4]
#define WS_MBC   26776
#define WS_C0    26777
// packed bf16 region (shorts): GA[0..4095] (rows 0..27 + ones row 31), GC5[4096..8191],
// fcw-frag[8192..10239], mm=2 mlp0 @32768, mm=3 mlp1 @49152
#define WS_PB    27392
#define WS_WO2T  (WS_PB + 5120)   // fp32 [21][128] Wo2 transposed
#define WS_SROW  (WS_PB + 7808)   // fp32 [28]
#define WS_EROW  (WS_PB + 7836)   // fp32 [28]
#define WS_GB    60160    // gru packed bf16 B-frags: 65536 ushort (32768 floats)
#define WS_AIR   92928    // air_feat buffer: bf16 [N_][128] ushort
#define TOKS     64       // attnmlp tokens per block

typedef __attribute__((ext_vector_type(8))) short bf16x8;
typedef __attribute__((ext_vector_type(4))) float f32x4;

extern "C" __device__ float __ocml_native_exp2_f32(float);   // single v_exp_f32

__device__ __forceinline__ unsigned short f2bf(float f){   // RNE fp32->bf16
    union { float f; unsigned u; } v; v.f = f;
    unsigned r = v.u + 0x7FFF + ((v.u >> 16) & 1);
    return (unsigned short)(r >> 16);
}
__device__ __forceinline__ float bf2f(unsigned short u){
    union { unsigned u; float f; } v; v.u = ((unsigned)u) << 16;
    return v.f;
}
// RNE pack of 2 f32 -> 1 u32 of 2 bf16 (low = a, high = b); single VALU instr
__device__ __forceinline__ unsigned cvtpk_bf16(float a, float b){
    unsigned r;
    asm("v_cvt_pk_bf16_f32 %0, %1, %2" : "=v"(r) : "v"(a), "v"(b));
    return r;
}

#define KL_SCALE (-1.4426950408889634f)   // -log2(e): R/Z gates
#define KN_SCALE ( 2.8853900817779268f)   // 2*log2(e): N/G gates

// ---------------- precompute + GRU B-frag pack (merged; blocks 384..639 = GB) ----
// WC[o][f] = sum_k gru_wih[o*128+k]*enc_air_w[k*15+f] is consumed exactly once per
// element by the GB pack -> inlined there; the old WC/WAP sections are deleted.
__global__ void precompute_kernel(
    const float* __restrict__ enc_air_w, const float* __restrict__ enc_air_b,
    const float* __restrict__ enc_m_w,  const float* __restrict__ enc_m_b,
    const float* __restrict__ gru_wih,  const float* __restrict__ gru_bih,
    const float* __restrict__ whh,
    const float* __restrict__ qln_w, const float* __restrict__ qln_b,
    const float* __restrict__ kln_w, const float* __restrict__ kln_b,
    const float* __restrict__ attn_in_w, const float* __restrict__ attn_in_b,
    const float* __restrict__ attn_out_w,
    const float* __restrict__ mlp0_w, const float* __restrict__ mlp1_w,
    float* __restrict__ ws)
{
    int i = blockIdx.x*blockDim.x + threadIdx.x;
    if (i < 6144) {
        // deleted (WC now inlined into GB pack below)
    } else if (i < 6528) {                // bc
        int o = i-6144; float a = gru_bih[o];
        for (int k=0;k<128;k++) a = fmaf(gru_wih[o*128+k], enc_air_b[k], a);
        ws[WS_BC+o] = a;
    } else if (i < 8576) {
        // deleted (WAP inlined)
    } else if (i < 24960) {               // wqp (fp32 copy)
        int idx = i-8576; int o = idx>>7, j = idx&127;
        ws[WS_WQP+idx] = attn_in_w[o*128+j]*qln_w[j];
    } else if (i < 25088) {               // sq
        int o = i-24960; float a=0.f;
        for (int j=0;j<128;j++) a = fmaf(attn_in_w[o*128+j], qln_w[j], a);
        ws[WS_SQ+o]=a;
    } else if (i < 25216) {               // eq
        int o = i-25088; float a = attn_in_b[o];
        for (int j=0;j<128;j++) a = fmaf(attn_in_w[o*128+j], qln_b[j], a);
        ws[WS_EQ+o]=a;
    } else if (i < 25728) {               // Kc
        int idx = i-25216; int o = idx>>2, f = idx&3; float a=0.f;
        for (int j=0;j<128;j++) a = fmaf(attn_in_w[(128+o)*128+j]*kln_w[j], enc_m_w[j*4+f], a);
        ws[WS_KC+idx]=a;
    } else if (i < 25856) {               // ek1
        int o = i-25728; float a=0.f;
        for (int j=0;j<128;j++) a = fmaf(attn_in_w[(128+o)*128+j]*kln_w[j], enc_m_b[j], a);
        ws[WS_EK1+o]=a;
    } else if (i < 25984) {               // sk
        int o = i-25856; float a=0.f;
        for (int j=0;j<128;j++) a = fmaf(attn_in_w[(128+o)*128+j], kln_w[j], a);
        ws[WS_SK+o]=a;
    } else if (i < 26112) {               // ek2
        int o = i-25984; float a = attn_in_b[128+o];
        for (int j=0;j<128;j++) a = fmaf(attn_in_w[(128+o)*128+j], kln_b[j], a);
        ws[WS_EK2+o]=a;
    } else if (i < 26624) {               // Vc
        int idx = i-26112; int o = idx>>2, f = idx&3; float a=0.f;
        for (int j=0;j<128;j++) a = fmaf(attn_in_w[(256+o)*128+j], enc_m_w[j*4+f], a);
        ws[WS_VC+idx]=a;
    } else if (i < 26752) {               // vb
        int o = i-26624; float a = attn_in_b[256+o];
        for (int j=0;j<128;j++) a = fmaf(attn_in_w[(256+o)*128+j], enc_m_b[j], a);
        ws[WS_VB+o]=a;
    } else if (i < 26756) {               // Mv
        int f = i-26752; float a=0.f;
        for (int j=0;j<128;j++) a += enc_m_w[j*4+f];
        ws[WS_MV+f]=a*(1.f/128.f);
    } else if (i < 26772) {               // QQ
        int idx = i-26756; int a4 = idx>>2, b4 = idx&3; float a=0.f;
        for (int j=0;j<128;j++) a = fmaf(enc_m_w[j*4+a4], enc_m_w[j*4+b4], a);
        ws[WS_QQ+idx]=a*(1.f/128.f);
    } else if (i < 26776) {               // qlin
        int f = i-26772; float a=0.f;
        for (int j=0;j<128;j++) a = fmaf(enc_m_b[j], enc_m_w[j*4+f], a);
        ws[WS_QLIN+f]=a*(2.f/128.f);
    } else if (i == 26776) {
        float a=0.f; for (int j=0;j<128;j++) a += enc_m_b[j];
        ws[WS_MBC]=a*(1.f/128.f);
    } else if (i == 26777) {
        float a=0.f; for (int j=0;j<128;j++) a = fmaf(enc_m_b[j], enc_m_b[j], a);
        ws[WS_C0]=a*(1.f/128.f);
    } else if (i >= 32768 && i < 98304) {
        // mlp bf16 B-frags (mm=2: mlp0, mm=3: mlp1)
        int idx = i - 32768;              // 0..65535
        int mm = idx>>14;
        if (mm >= 2) {
            int i8 = idx & 7, l = (idx>>3)&63, p = (idx>>9)&3, wv = (idx>>11)&7;
            int n = 16*wv + (l&15);
            int k = 32*p + ((l>>4)<<3) + i8;
            float v = (mm==2) ? mlp0_w[n*128+k] : mlp1_w[n*128+k];
            ((unsigned short*)(ws+WS_PB))[idx] = f2bf(v);
        }
    } else if (i >= 98304) {
        // ---- GRU bf16 B-frag pack (was pack_gru_kernel); WC/WAP inlined ----
        int idx = i - 98304;              // 0..65535
        int i8 = idx&7, l=(idx>>3)&63, w=(idx>>9)&7, f=idx>>12;
        int n = 16*w + (l&15);
        int k = ((l>>4)<<3) + i8;         // 0..31 within chunk
        float v = 0.f;
        if (f < 5) {
            int kk = f*32 + k;
            if (kk < 128) v = whh[n*128 + kk];
            else { int kl = kk-128;
                   if (kl < 15){ float a=0.f;
                       for (int q=0;q<128;q++) a = fmaf(gru_wih[n*128+q], enc_air_w[q*15+kl], a);
                       v = a; } }
            v *= KL_SCALE;
        } else if (f < 10) {
            int kk = (f-5)*32 + k;
            if (kk < 128) v = whh[(128+n)*128 + kk];
            else { int kl = kk-128;
                   if (kl < 15){ float a=0.f;
                       for (int q=0;q<128;q++) a = fmaf(gru_wih[(128+n)*128+q], enc_air_w[q*15+kl], a);
                       v = a; } }
            v *= KL_SCALE;
        } else if (f < 14) {
            v = whh[(256+n)*128 + (f-10)*32 + k] * KN_SCALE;
        } else if (f == 14) {
            if (k < 15){ float a=0.f;
                for (int q=0;q<128;q++) a = fmaf(gru_wih[(256+n)*128+q], enc_air_w[q*15+k], a);
                v = a * KN_SCALE; }
        } else {
            if (k < 15) v = enc_air_w[n*15+k];
        }
        ((unsigned short*)(ws+WS_GB))[idx] = f2bf(v);
    }
}

// ---------------- pack2: GA (score projections + ones-row), Srow/Erow, Wo2T ------
__global__ void pack2_kernel(const float* __restrict__ wo, const float* __restrict__ bo,
                             float* __restrict__ ws)
{
    int i = blockIdx.x*blockDim.x + threadIdx.x;   // 27*256 = 6912
    if (i < 4096) {                                // GA packed bf16 (2 col-tiles x 4 ksteps)
        int i8=i&7, l=(i>>3)&63, p=(i>>9)&3, ct=(i>>11)&1;
        int r = 16*ct + (l&15);
        int k = 32*p + ((l>>4)<<3) + i8;
        float v = 0.f;
        if (r < 28){
            int h = r/7, u = r - h*7;
            float a = 0.f;
            for (int d5=0; d5<32; d5++){
                int d = h*32 + d5;
                float c = (u<4) ? ws[WS_KC + d*4 + u]
                        : (u==4) ? ws[WS_EK1 + d]
                        : (u==5) ? ws[WS_SK + d]
                        :          ws[WS_EK2 + d];
                a = fmaf(c, ws[WS_WQP + d*128 + k], a);
            }
            v = a;
        } else if (r == 31) {
            v = 1.f;                               // ones-row: GEMM A col 31 = sum(X)
        }
        ((unsigned short*)(ws+WS_PB))[i] = f2bf(v);
    } else if (i < 4152) {                         // Srow / Erow
        int j = i - 4096; int r = j % 28; int era = j / 28;
        int h = r/7, u = r - h*7;
        float a = 0.f;
        for (int d5=0; d5<32; d5++){
            int d = h*32 + d5;
            float c = (u<4) ? ws[WS_KC + d*4 + u]
                    : (u==4) ? ws[WS_EK1 + d]
                    : (u==5) ? ws[WS_SK + d]
                    :          ws[WS_EK2 + d];
            a = fmaf(c, ws[(era ? WS_EQ : WS_SQ) + d], a);
        }
        ws[(era ? WS_EROW : WS_SROW) + r] = a;
    } else if (i >= 4224 && i < 6912) {            // Wo2T[c][o]; c=20 -> bo
        int j = i - 4224; int c = j>>7, o = j&127;
        float a;
        if (c == 20) a = bo[o];
        else {
            int h = c/5, u = c - h*5;
            a = 0.f;
            for (int d5=0; d5<32; d5++){
                int d = h*32 + d5;
                float cv = (u<4) ? ws[WS_VC + d*4 + u] : ws[WS_VB + d];
                a = fmaf(wo[o*128 + d], cv, a);
            }
        }
        ws[WS_WO2T + c*128 + o] = a;
    }
}

// ---------------- pack3: GC5 = mlp0_w @ Wo2 + fcw B-frag ----------------
__global__ void pack3_kernel(const float* __restrict__ mlp0_w,
                             const float* __restrict__ fcw,
                             float* __restrict__ ws)
{
    int i = blockIdx.x*blockDim.x + threadIdx.x;   // 24 blocks x 256 = 6144
    if (i < 4096){
        int i8=i&7, l=(i>>3)&63, w=(i>>9)&7;
        int n = 16*w + (l&15);
        int c = ((l>>4)<<3) + i8;                  // 0..31 (cols 128..159 of Wc)
        float v = 0.f;
        if (c < 21){
            float a = 0.f;
            const float* wo2 = ws + WS_WO2T + c*128;
            for (int o=0;o<128;o++) a = fmaf(mlp0_w[n*128+o], wo2[o], a);
            v = a;
        }
        ((unsigned short*)(ws+WS_PB))[4096 + i] = f2bf(v);
    } else {
        // fcw B-frag: col 0 = fcw[k], other cols 0.  2048 shorts at pb[8192..]
        int j = i - 4096;                          // 0..2047
        int i8=j&7, l=(j>>3)&63, p=(j>>9)&3;
        int k = 32*p + ((l>>4)<<3) + i8;
        float v = ((l&15)==0) ? fcw[k] : 0.f;
        ((unsigned short*)(ws+WS_PB))[8192 + j] = f2bf(v);
    }
}

// ---------------- Kernel A v9: GRU (unchanged from R9 — best measured) -----------
__global__ __launch_bounds__(512) void gru_kernel(
    const float* __restrict__ obs, const float* __restrict__ h0,
    const float* __restrict__ bhh, const float* __restrict__ ba,
    const float* __restrict__ ws,
    unsigned short* __restrict__ air, float* __restrict__ out)
{
    __shared__ __align__(16) unsigned short Abf[2][16*136];      // h bf16, pitch 136
    __shared__ __align__(16) unsigned short obs_lds[64*16*24];   // [s][tok][24] bf16
    __shared__ __align__(16) unsigned short zero16[8];

    const int t = threadIdx.x;
    const int w = t>>6;          // wave 0..7
    const int l = t&63;
    const int quad = l>>4;
    const int col  = l&15;
    const int jj   = 16*w + col; // output column j
    const int row0 = blockIdx.x*16;

    const unsigned short* gb = (const unsigned short*)(ws + WS_GB);
    bf16x8 bf[16];
    #pragma unroll
    for (int f=0; f<16; f++) bf[f] = *(const bf16x8*)&gb[(f*8 + w)*512 + l*8];

    // scaled biases -> loop-invariant MFMA C-operand splats
    const float bcrt = KL_SCALE*(ws[WS_BC+jj]     + bhh[jj]);
    const float bczt = KL_SCALE*(ws[WS_BC+128+jj] + bhh[128+jj]);
    const float bcn  = KN_SCALE*ws[WS_BC+256+jj];
    const float bhn  = KN_SCALE*bhh[256+jj];
    const float baj  = ba[jj];
    const f32x4 cR = {bcrt,bcrt,bcrt,bcrt};
    const f32x4 cZ = {bczt,bczt,bczt,bczt};
    const f32x4 cG = {bcn,bcn,bcn,bcn};
    const f32x4 cE = {baj,baj,baj,baj};
    const f32x4 cN = {bhn,bhn,bhn,bhn};

    float hreg[4];
    #pragma unroll
    for (int reg=0; reg<4; reg++)
        hreg[reg] = h0[(size_t)(row0+quad*4+reg)*128 + jj];

    if (t < 8) zero16[t] = 0;

    {
        int rr = t>>5, c0i = (t&31)*4;
        float4 hv = *(const float4*)&h0[(size_t)(row0+rr)*128 + c0i];
        unsigned lo = cvtpk_bf16(hv.x, hv.y);
        unsigned hi = cvtpk_bf16(hv.z, hv.w);
        unsigned long long pk = (unsigned long long)lo | ((unsigned long long)hi << 32);
        *(unsigned long long*)&Abf[0][rr*136 + c0i] = pk;
    }

    #pragma unroll
    for (int it=0; it<8; it++){
        int pair = it*128 + (t>>2);      // (tok,s) pair, 4 lanes each
        int sub  = t&3;
        int tok = pair>>6, s = pair&63;
        const float* op = &obs[((size_t)(row0+tok)*64 + s)*15 + sub*4];
        float o0 = op[0];
        float o1 = (sub*4+1<15) ? op[1] : 0.f;
        float o2 = (sub*4+2<15) ? op[2] : 0.f;
        float o3 = (sub*4+3<15) ? op[3] : 0.f;
        unsigned lo = cvtpk_bf16(o0, o1);
        unsigned hi = cvtpk_bf16(o2, o3);
        unsigned long long pk = (unsigned long long)lo | ((unsigned long long)hi << 32);
        *(unsigned long long*)&obs_lds[(s*16+tok)*24 + sub*4] = pk;
    }
    __syncthreads();

    // per-reg air pointers (reg offsets exceed the 13-bit store immediate)
    unsigned short* ap0 = air + (size_t)(row0 + quad*4 + 0)*8192 + jj;
    unsigned short* ap1 = air + (size_t)(row0 + quad*4 + 1)*8192 + jj;
    unsigned short* ap2 = air + (size_t)(row0 + quad*4 + 2)*8192 + jj;
    unsigned short* ap3 = air + (size_t)(row0 + quad*4 + 3)*8192 + jj;
    const int anb = (quad*4)*136 + jj;   // An short-index base (rows +136)

    // prologue: obs-only MFMA accs for step 0 (biases ride in C)
    f32x4 oR, oZ, oG, oE;
    {
        const unsigned short* osrc = (quad<2)
            ? &obs_lds[(0*16+col)*24 + quad*8] : &zero16[0];
        bf16x8 a4 = *(const bf16x8*)osrc;
        oR = __builtin_amdgcn_mfma_f32_16x16x32_bf16(a4, bf[4],  cR, 0,0,0);
        oZ = __builtin_amdgcn_mfma_f32_16x16x32_bf16(a4, bf[9],  cZ, 0,0,0);
        oG = __builtin_amdgcn_mfma_f32_16x16x32_bf16(a4, bf[14], cG, 0,0,0);
        oE = __builtin_amdgcn_mfma_f32_16x16x32_bf16(a4, bf[15], cE, 0,0,0);
    }

    unsigned short* const A0 = &Abf[0][0];
    unsigned short* const A1 = &Abf[1][0];

// R7 body: single 4-deep accumulate chains; OFF = air store offset (0 or 128)
#define GRU_STEP(S, AC, AN, OFF)                                                   \
    {                                                                              \
        bf16x8 a0 = *(const bf16x8*)&(AC)[col*136 +  0 + quad*8];                  \
        bf16x8 a1 = *(const bf16x8*)&(AC)[col*136 + 32 + quad*8];                  \
        bf16x8 a2 = *(const bf16x8*)&(AC)[col*136 + 64 + quad*8];                  \
        bf16x8 a3 = *(const bf16x8*)&(AC)[col*136 + 96 + quad*8];                  \
        f32x4 aR = oR, aZ = oZ;                                                    \
        f32x4 aN = cN;                                                             \
        aR = __builtin_amdgcn_mfma_f32_16x16x32_bf16(a0, bf[0],  aR, 0,0,0);       \
        aR = __builtin_amdgcn_mfma_f32_16x16x32_bf16(a1, bf[1],  aR, 0,0,0);       \
        aR = __builtin_amdgcn_mfma_f32_16x16x32_bf16(a2, bf[2],  aR, 0,0,0);       \
        aR = __builtin_amdgcn_mfma_f32_16x16x32_bf16(a3, bf[3],  aR, 0,0,0);       \
        aZ = __builtin_amdgcn_mfma_f32_16x16x32_bf16(a0, bf[5],  aZ, 0,0,0);       \
        aZ = __builtin_amdgcn_mfma_f32_16x16x32_bf16(a1, bf[6],  aZ, 0,0,0);       \
        aZ = __builtin_amdgcn_mfma_f32_16x16x32_bf16(a2, bf[7],  aZ, 0,0,0);       \
        aZ = __builtin_amdgcn_mfma_f32_16x16x32_bf16(a3, bf[8],  aZ, 0,0,0);       \
        aN = __builtin_amdgcn_mfma_f32_16x16x32_bf16(a0, bf[10], aN, 0,0,0);       \
        aN = __builtin_amdgcn_mfma_f32_16x16x32_bf16(a1, bf[11], aN, 0,0,0);       \
        aN = __builtin_amdgcn_mfma_f32_16x16x32_bf16(a2, bf[12], aN, 0,0,0);       \
        aN = __builtin_amdgcn_mfma_f32_16x16x32_bf16(a3, bf[13], aN, 0,0,0);       \
        f32x4 nR, nZ, nG, nE;                                                      \
        if ((S) < 63){                                                             \
            const unsigned short* osrc = (quad<2)                                  \
                ? &obs_lds[(((S)+1)*16+col)*24 + quad*8] : &zero16[0];             \
            bf16x8 a4 = *(const bf16x8*)osrc;                                      \
            nR = __builtin_amdgcn_mfma_f32_16x16x32_bf16(a4, bf[4],  cR, 0,0,0);   \
            nZ = __builtin_amdgcn_mfma_f32_16x16x32_bf16(a4, bf[9],  cZ, 0,0,0);   \
            nG = __builtin_amdgcn_mfma_f32_16x16x32_bf16(a4, bf[14], cG, 0,0,0);   \
            nE = __builtin_amdgcn_mfma_f32_16x16x32_bf16(a4, bf[15], cE, 0,0,0);   \
        }                                                                          \
        float hnv[4], avv[4];                                                      \
        _Pragma("unroll")                                                          \
        for (int reg=0; reg<4; reg++){                                             \
            float rg = __builtin_amdgcn_rcpf(1.f + __ocml_native_exp2_f32(aR[reg]));\
            float zg = __builtin_amdgcn_rcpf(1.f + __ocml_native_exp2_f32(aZ[reg]));\
            float nx = fmaf(rg, aN[reg], oG[reg]);                                 \
            float e2 = __ocml_native_exp2_f32(nx);                                 \
            float ng = 1.f - 2.f*__builtin_amdgcn_rcpf(e2 + 1.f);                  \
            float hn = fmaf(zg, hreg[reg]-ng, ng);                                 \
            hreg[reg] = hn;                                                        \
            hnv[reg] = hn;                                                         \
            avv[reg] = hn + oE[reg];                                               \
        }                                                                          \
        unsigned ph01 = cvtpk_bf16(hnv[0], hnv[1]);                                \
        unsigned ph23 = cvtpk_bf16(hnv[2], hnv[3]);                                \
        unsigned pa01 = cvtpk_bf16(avv[0], avv[1]);                                \
        unsigned pa23 = cvtpk_bf16(avv[2], avv[3]);                                \
        (AN)[anb        ] = (unsigned short)ph01;                                  \
        (AN)[anb + 136  ] = (unsigned short)(ph01 >> 16);                          \
        (AN)[anb + 272  ] = (unsigned short)ph23;                                  \
        (AN)[anb + 408  ] = (unsigned short)(ph23 >> 16);                          \
        ap0[OFF] = (unsigned short)pa01;  ap1[OFF] = (unsigned short)(pa01 >> 16); \
        ap2[OFF] = (unsigned short)pa23;  ap3[OFF] = (unsigned short)(pa23 >> 16); \
        if ((S) < 63){ oR = nR; oZ = nZ; oG = nG; oE = nE; }                       \
        asm volatile("s_waitcnt lgkmcnt(0)" ::: "memory");                         \
        __builtin_amdgcn_s_barrier();                                              \
        __builtin_amdgcn_sched_barrier(0);                                         \
    }

    for (int s = 0; s < 64; s += 2){
        GRU_STEP(s,   A0, A1, 0)
        GRU_STEP(s+1, A1, A0, 128)
        ap0 += 256; ap1 += 256; ap2 += 256; ap3 += 256;
    }
#undef GRU_STEP

    #pragma unroll
    for (int reg=0; reg<4; reg++)
        out[(size_t)N_ + (size_t)(row0+quad*4+reg)*128 + jj] = hreg[reg];
}

// ---------------- Kernel B v6: attn+MLP (unchanged from R9) ----------------
__global__ __launch_bounds__(512) void attnmlp_kernel(
    const float* __restrict__ obs,
    const float* __restrict__ ws,
    const float* __restrict__ b0, const float* __restrict__ b1,
    const float* __restrict__ fcb,
    const unsigned short* __restrict__ air, float* __restrict__ out)
{
    __shared__ __align__(16) unsigned short U_bf[TOKS*168];
    __shared__ __align__(16) unsigned short H1_bf[TOKS*136];
    __shared__ float praw[TOKS*28];
    __shared__ float obs_m[TOKS][8];
    __shared__ float sm_s[TOKS], s2_s[TOKS];
    __shared__ float kmu_s[TOKS][2], krs_s[TOKS][2];
    __shared__ int   kmask_s[TOKS][2];
    __shared__ float sero[56];

    const int t = threadIdx.x;
    const int w = t>>6;
    const int l = t&63;
    const int quad = l>>4;
    const int col  = l&15;
    const int jj   = 16*w + col;
    const int n0 = blockIdx.x*TOKS;

    const unsigned short* pb = (const unsigned short*)(ws + WS_PB);

    {
        const int tok0 = t>>3, sub = t&7;
        const unsigned short* apx = &air[(size_t)(n0+tok0)*128 + sub*16];
        uint4 x0 = *(const uint4*)apx;
        uint4 x1 = *(const uint4*)(apx+8);
        *(uint4*)&U_bf[tok0*168 + sub*16]     = x0;
        *(uint4*)&U_bf[tok0*168 + sub*16 + 8] = x1;
        if (sub < 5){
            #pragma unroll
            for (int c=0;c<4;c++) U_bf[tok0*168 + 148 + sub*4 + c] = 0;
        }
        obs_m[tok0][sub] = obs[(size_t)(n0+tok0)*15 + sub];
    }
    if (t < 128){
        int rr = t>>1, mi = t&1;
        const float* mp = &obs[(size_t)(n0+rr)*15 + mi*4];
        float m0=mp[0], m1=mp[1], m2=mp[2], m3=mp[3];
        const float tol1 = 1e-8f + 1e-5f, tol0 = 1e-8f;
        kmask_s[rr][mi] = (fabsf(m0-1.f)<=tol1)&&(fabsf(m1)<=tol0)&&
                          (fabsf(m2-1.f)<=tol1)&&(fabsf(m3)<=tol0);
        float mv[4]={m0,m1,m2,m3};
        float mu = ws[WS_MBC];
        #pragma unroll
        for (int f=0;f<4;f++) mu = fmaf(ws[WS_MV+f], mv[f], mu);
        float e2 = ws[WS_C0];
        #pragma unroll
        for (int a4=0;a4<4;a4++){
            e2 = fmaf(ws[WS_QLIN+a4], mv[a4], e2);
            #pragma unroll
            for (int b4=0;b4<4;b4++) e2 = fmaf(ws[WS_QQ+a4*4+b4]*mv[a4], mv[b4], e2);
        }
        float var = e2 - mu*mu;
        kmu_s[rr][mi]=mu; krs_s[rr][mi]=rsqrtf(var+1e-5f);
    }
    if (t < 56) sero[t] = ws[WS_SROW + t];
    __syncthreads();

    {
        const int tt = w>>1, ct = w&1;
        const int jA = ct*16 + col;
        bf16x8 afr[4];
        #pragma unroll
        for (int p=0;p<4;p++)
            afr[p] = *(const bf16x8*)&U_bf[(tt*16+col)*168 + p*32 + quad*8];
        f32x4 acc = {0.f,0.f,0.f,0.f};
        #pragma unroll
        for (int p=0;p<4;p++)
            acc = __builtin_amdgcn_mfma_f32_16x16x32_bf16(afr[p], *(const bf16x8*)&pb[((ct*4+p)*64 + l)*8], acc, 0,0,0);
        if (ct == 1){
            f32x4 accX = {0.f,0.f,0.f,0.f};
            #pragma unroll
            for (int p=0;p<4;p++)
                accX = __builtin_amdgcn_mfma_f32_16x16x32_bf16(afr[p], afr[p], accX, 0,0,0);
            if ((col>>2) == quad) s2_s[tt*16+col] = accX[col&3];
            if (col == 15){
                #pragma unroll
                for (int reg=0;reg<4;reg++) sm_s[tt*16+quad*4+reg] = acc[reg];
            }
        }
        if (jA < 28){
            #pragma unroll
            for (int reg=0;reg<4;reg++)
                praw[(tt*16+quad*4+reg)*28 + jA] = acc[reg];
        }
    }
    __syncthreads();

    if (t < TOKS*4){
        const int tok = t>>2, h = t&3;
        float mu = sm_s[tok]*(1.f/128.f);
        float var = s2_s[tok]*(1.f/128.f) - mu*mu;
        float rs = rsqrtf(var + 1e-5f);
        const float* pr = &praw[tok*28 + h*7];
        float P[7];
        #pragma unroll
        for (int u=0;u<7;u++)
            P[u] = fmaf(rs, pr[u] - mu*sero[h*7+u], sero[28 + h*7+u]);
        const float T0=P[0],T1=P[1],T2=P[2],T3=P[3],Pa=P[4],Pb=P[5],Pc=P[6];
        const float4 m0v = *(const float4*)&obs_m[tok][0];
        const float4 m1v = *(const float4*)&obs_m[tok][4];
        // scale folded with log2(e): softmax(s) via exp2 — exact identity
        const float scale = 0.17677669529663687f * 1.4426950408889634f;
        float d0 = fmaf(T0,m0v.x, fmaf(T1,m0v.y, fmaf(T2,m0v.z, fmaf(T3,m0v.w, Pa))));
        float d1 = fmaf(T0,m1v.x, fmaf(T1,m1v.y, fmaf(T2,m1v.z, fmaf(T3,m1v.w, Pa))));
        float s0 = fmaf(krs_s[tok][0], d0 - kmu_s[tok][0]*Pb, Pc) * scale;
        float s1 = fmaf(krs_s[tok][1], d1 - kmu_s[tok][1]*Pb, Pc) * scale;
        int msk0 = kmask_s[tok][0], msk1 = kmask_s[tok][1];
        float a0, a1;
        if (msk0 && msk1){
            a0=0.f; a1=0.f;
            if (h==0) U_bf[tok*168 + 148] = 0;
        } else {
            if (h==0) U_bf[tok*168 + 148] = 0x3F80;
            if (msk0)      { a0=0.f; a1=1.f; }
            else if (msk1) { a0=1.f; a1=0.f; }
            else {
                float mx = fmaxf(s0,s1);
                float e0 = __ocml_native_exp2_f32(s0-mx);
                float e1 = __ocml_native_exp2_f32(s1-mx);
                float inv = 1.f/(e0+e1);
                a0 = e0*inv; a1 = e1*inv;
            }
        }
        int cb = tok*168 + 128 + h*5;
        unsigned y01 = cvtpk_bf16(fmaf(a0, m0v.x, a1*m1v.x), fmaf(a0, m0v.y, a1*m1v.y));
        unsigned y23 = cvtpk_bf16(fmaf(a0, m0v.z, a1*m1v.z), fmaf(a0, m0v.w, a1*m1v.w));
        U_bf[cb+0] = (unsigned short)y01;
        U_bf[cb+1] = (unsigned short)(y01 >> 16);
        U_bf[cb+2] = (unsigned short)y23;
        U_bf[cb+3] = (unsigned short)(y23 >> 16);
        U_bf[cb+4] = f2bf(a0 + a1);
    }
    __syncthreads();

    {
        bf16x8 bfr[5];
        #pragma unroll
        for (int p=0;p<4;p++) bfr[p] = *(const bf16x8*)&pb[((2*32 + w*4 + p)*64 + l)*8];
        bfr[4] = *(const bf16x8*)&pb[4096 + (w*64 + l)*8];
        f32x4 acc[4];
        #pragma unroll
        for (int tt=0;tt<4;tt++) acc[tt] = (f32x4){0.f,0.f,0.f,0.f};
        #pragma unroll
        for (int p=0;p<5;p++){
            const int ko = p*32 + quad*8;
            #pragma unroll
            for (int tt=0;tt<4;tt++){
                bf16x8 a = *(const bf16x8*)&U_bf[(tt*16+col)*168 + ko];
                acc[tt] = __builtin_amdgcn_mfma_f32_16x16x32_bf16(a, bfr[p], acc[tt], 0,0,0);
            }
        }
        const float b0j = b0[jj];
        #pragma unroll
        for (int tt=0;tt<4;tt++){
            float vv[4];
            #pragma unroll
            for (int reg=0;reg<4;reg++){
                float v = acc[tt][reg] + b0j;
                vv[reg] = (v > 0.f) ? v : 0.01f*v;
            }
            unsigned p01 = cvtpk_bf16(vv[0], vv[1]);
            unsigned p23 = cvtpk_bf16(vv[2], vv[3]);
            int base = (tt*16 + quad*4)*136 + jj;
            H1_bf[base      ] = (unsigned short)p01;
            H1_bf[base + 136] = (unsigned short)(p01 >> 16);
            H1_bf[base + 272] = (unsigned short)p23;
            H1_bf[base + 408] = (unsigned short)(p23 >> 16);
        }
    }
    __syncthreads();

    {
        bf16x8 bfr[4];
        #pragma unroll
        for (int p=0;p<4;p++) bfr[p] = *(const bf16x8*)&pb[((3*32 + w*4 + p)*64 + l)*8];
        f32x4 acc[4];
        #pragma unroll
        for (int tt=0;tt<4;tt++) acc[tt] = (f32x4){0.f,0.f,0.f,0.f};
        #pragma unroll
        for (int p=0;p<4;p++){
            const int ko = p*32 + quad*8;
            #pragma unroll
            for (int tt=0;tt<4;tt++){
                bf16x8 a = *(const bf16x8*)&H1_bf[(tt*16+col)*136 + ko];
                acc[tt] = __builtin_amdgcn_mfma_f32_16x16x32_bf16(a, bfr[p], acc[tt], 0,0,0);
            }
        }
        const float b1j = b1[jj];
        #pragma unroll
        for (int tt=0;tt<4;tt++){
            float vv[4];
            #pragma unroll
            for (int reg=0;reg<4;reg++){
                float v = acc[tt][reg] + b1j;
                vv[reg] = (v > 0.f) ? v : 0.01f*v;
            }
            unsigned p01 = cvtpk_bf16(vv[0], vv[1]);
            unsigned p23 = cvtpk_bf16(vv[2], vv[3]);
            int base = (tt*16 + quad*4)*168 + jj;
            U_bf[base      ] = (unsigned short)p01;
            U_bf[base + 168] = (unsigned short)(p01 >> 16);
            U_bf[base + 336] = (unsigned short)p23;
            U_bf[base + 504] = (unsigned short)(p23 >> 16);
        }
    }
    __syncthreads();

    if (w < 4){
        f32x4 acc = {0.f,0.f,0.f,0.f};
        #pragma unroll
        for (int p=0;p<4;p++){
            bf16x8 a = *(const bf16x8*)&U_bf[(w*16+col)*168 + p*32 + quad*8];
            bf16x8 b = *(const bf16x8*)&pb[8192 + (p*64 + l)*8];
            acc = __builtin_amdgcn_mfma_f32_16x16x32_bf16(a, b, acc, 0, 0, 0);
        }
        if (col == 0){
            float fb = fcb[0];
            #pragma unroll
            for (int reg=0;reg<4;reg++)
                out[n0 + w*16 + quad*4 + reg] = acc[reg] + fb;
        }
    }
}

extern "C" void kernel_launch(void* const* d_in, const int* in_sizes, int n_in,
                              void* d_out, int out_size, void* d_ws, size_t ws_size,
                              hipStream_t stream) {
    const float* obs       = (const float*)d_in[0];
    const float* h0        = (const float*)d_in[1];
    const float* enc_air_w = (const float*)d_in[2];
    const float* enc_air_b = (const float*)d_in[3];
    const float* enc_m_w   = (const float*)d_in[4];
    const float* enc_m_b   = (const float*)d_in[5];
    const float* gru_wih   = (const float*)d_in[6];
    const float* gru_whh   = (const float*)d_in[7];
    const float* gru_bih   = (const float*)d_in[8];
    const float* gru_bhh   = (const float*)d_in[9];
    const float* qln_w     = (const float*)d_in[10];
    const float* qln_b     = (const float*)d_in[11];
    const float* kln_w     = (const float*)d_in[12];
    const float* kln_b     = (const float*)d_in[13];
    const float* attn_in_w = (const float*)d_in[14];
    const float* attn_in_b = (const float*)d_in[15];
    const float* attn_out_w= (const float*)d_in[16];
    const float* attn_out_b= (const float*)d_in[17];
    const float* mlp0_w    = (const float*)d_in[18];
    const float* mlp0_b    = (const float*)d_in[19];
    const float* mlp1_w    = (const float*)d_in[20];
    const float* mlp1_b    = (const float*)d_in[21];
    const float* fco_w     = (const float*)d_in[22];
    const float* fco_b     = (const float*)d_in[23];
    float* out = (float*)d_out;
    float* ws  = (float*)d_ws;
    unsigned short* air = (unsigned short*)(ws + WS_AIR);

    // merged precompute + GRU B-frag pack: blocks 0..383 = folded weights,
    // blocks 384..639 = GB pack (WC/WAP inlined, no dependency)
    precompute_kernel<<<dim3(640), dim3(256), 0, stream>>>(
        enc_air_w, enc_air_b, enc_m_w, enc_m_b, gru_wih, gru_bih, gru_whh,
        qln_w, qln_b, kln_w, kln_b, attn_in_w, attn_in_b,
        attn_out_w, mlp0_w, mlp1_w, ws);

    pack2_kernel<<<dim3(27), dim3(256), 0, stream>>>(attn_out_w, attn_out_b, ws);
    pack3_kernel<<<dim3(24), dim3(256), 0, stream>>>(mlp0_w, fco_w, ws);

    gru_kernel<<<dim3(256), dim3(512), 0, stream>>>(
        obs, h0, gru_bhh, enc_air_b, ws, air, out);

    attnmlp_kernel<<<dim3(N_/TOKS), dim3(512), 0, stream>>>(
        obs, ws, mlp0_b, mlp1_b, fco_b, air, out);
}